// Round 1
// baseline (3262.262 us; speedup 1.0000x reference)
//
#include <hip/hip_runtime.h>
#include <math.h>

#define BB 8
#define LL 512
#define CC 862
#define PP 96
#define DD 128
#define II 256
#define NHH 4
#define DHH 64
#define SS 862            // mLSTM sequence length = C
#define BC (BB*CC)        // 6896 rows

// ---------------------------------------------------------------------------
// Fused series-decomp + DLinear heads + P->D projection.
// One block per (b, 8-channel tile). LDS holds x_enc rows (with replicate pad)
// and the moving average; res = xe - mm is formed on the fly.
// ---------------------------------------------------------------------------
__global__ __launch_bounds__(256) void head_kernel(
    const float* __restrict__ xe,
    const float* __restrict__ Ws, const float* __restrict__ bs,
    const float* __restrict__ Wt, const float* __restrict__ bt,
    const float* __restrict__ Wp1, const float* __restrict__ bp1,
    float* __restrict__ xout)
{
  __shared__ float xel[536 * 8];
  __shared__ float mml[512 * 8];
  __shared__ float x0l[8][100];
  int tid = threadIdx.x;
  int blk = blockIdx.x;
  int b = blk / 108, ct = blk % 108;
  int c0 = ct * 8;
  // load x_enc rows l-12..l+12 range with edge clamp (== replicate pad)
  for (int j = 0; j < 17; ++j) {
    int idx = tid + j * 256;
    if (idx < 4288) {
      int li = idx >> 3, cl = idx & 7;
      int l = li - 12; l = l < 0 ? 0 : (l > 511 ? 511 : l);
      int c = c0 + cl; if (c > CC - 1) c = CC - 1;
      xel[idx] = xe[((size_t)b * LL + l) * CC + c];
    }
  }
  __syncthreads();
  // moving average (kernel 25)
  for (int j = 0; j < 16; ++j) {
    int idx = tid + j * 256;      // 4096 = 512*8
    int l = idx >> 3, cl = idx & 7;
    float s = 0.f;
    #pragma unroll 5
    for (int o = 0; o < 25; ++o) s += xel[(l + o) * 8 + cl];
    mml[idx] = s * (1.f / 25.f);
  }
  __syncthreads();
  // x0[c][p] = sum_l res*Ws + mm*Wt + bs + bt  (res = xe - mm)
  for (int j = 0; j < 3; ++j) {
    int o = tid + j * 256;        // 768 = 8*96
    int cl = o & 7, p = o >> 3;
    const float* wsr = Ws + p * 512;
    const float* wtr = Wt + p * 512;
    float acc = bs[p] + bt[p];
    for (int l = 0; l < 512; ++l) {
      float xv = xel[(l + 12) * 8 + cl];
      float mv = mml[l * 8 + cl];
      acc += (xv - mv) * wsr[l] + mv * wtr[l];
    }
    x0l[cl][p] = acc;
  }
  __syncthreads();
  // x[c][d] = x0 @ Wp1^T + bp1
  for (int j = 0; j < 4; ++j) {
    int o = tid + j * 256;        // 1024 = 8*128
    int d = o & 127, cl = o >> 7;
    int c = c0 + cl;
    if (c < CC) {
      const float* wp = Wp1 + d * 96;
      float acc = bp1[d];
      #pragma unroll 8
      for (int p = 0; p < 96; ++p) acc += x0l[cl][p] * wp[p];
      xout[((size_t)b * CC + c) * DD + d] = acc;
    }
  }
}

// ---------------------------------------------------------------------------
// Row LayerNorm (D=128), weight-only. One wave per row, 4 rows/block.
// ---------------------------------------------------------------------------
__global__ __launch_bounds__(256) void ln_kernel(
    const float* __restrict__ x, const float* __restrict__ g,
    float* __restrict__ y, int nrows)
{
  int row = blockIdx.x * 4 + (threadIdx.x >> 6);
  int lane = threadIdx.x & 63;
  if (row >= nrows) return;
  const float* xr = x + (size_t)row * DD;
  float a = xr[lane], b2 = xr[lane + 64];
  float s = a + b2, sq = a * a + b2 * b2;
  #pragma unroll
  for (int d = 1; d < 64; d <<= 1) { s += __shfl_xor(s, d); sq += __shfl_xor(sq, d); }
  float mean = s * (1.f / 128.f);
  float var = sq * (1.f / 128.f) - mean * mean;
  float r = rsqrtf(var + 1e-5f);
  y[(size_t)row * DD + lane] = (a - mean) * r * g[lane];
  y[(size_t)row * DD + 64 + lane] = (b2 - mean) * r * g[64 + lane];
}

// ---------------------------------------------------------------------------
// fp32 tiled GEMM: C[M,N] (+= / =) A[M,K](lda) @ B[K,N](ldb) (+bias)
// BM=BN=64, BK=16, 256 threads, 4x4 micro-tile. K%16==0, N%64==0.
// ---------------------------------------------------------------------------
template<bool ACC, bool BIAS>
__global__ __launch_bounds__(256) void gemm_f32(
    const float* __restrict__ A, int lda,
    const float* __restrict__ Bm, int ldb,
    float* __restrict__ Cm, int ldc,
    const float* __restrict__ bias,
    int M, int N, int K)
{
  __shared__ float As[16][68];
  __shared__ float Bs[16][64];
  int tid = threadIdx.x;
  int tx = tid & 15, ty = tid >> 4;
  int m0 = blockIdx.y * 64;
  int n0 = blockIdx.x * 64;
  float acc[4][4] = {};
  for (int k0 = 0; k0 < K; k0 += 16) {
    #pragma unroll
    for (int j = 0; j < 4; ++j) {
      int idx = tid + j * 256;
      int r = idx >> 4, kk = idx & 15;
      int row = m0 + r;
      As[kk][r] = (row < M) ? A[(size_t)row * lda + k0 + kk] : 0.f;
    }
    #pragma unroll
    for (int j = 0; j < 4; ++j) {
      int idx = tid + j * 256;
      int r = idx >> 6, cc = idx & 63;
      Bs[r][cc] = Bm[(size_t)(k0 + r) * ldb + n0 + cc];
    }
    __syncthreads();
    #pragma unroll
    for (int kk = 0; kk < 16; ++kk) {
      float4 av = *(const float4*)&As[kk][ty * 4];
      float4 bv = *(const float4*)&Bs[kk][tx * 4];
      float a0[4] = {av.x, av.y, av.z, av.w};
      float b0[4] = {bv.x, bv.y, bv.z, bv.w};
      #pragma unroll
      for (int i = 0; i < 4; ++i)
        #pragma unroll
        for (int j2 = 0; j2 < 4; ++j2) acc[i][j2] += a0[i] * b0[j2];
    }
    __syncthreads();
  }
  #pragma unroll
  for (int i = 0; i < 4; ++i) {
    int row = m0 + ty * 4 + i;
    if (row < M) {
      float* cp = Cm + (size_t)row * ldc + n0 + tx * 4;
      #pragma unroll
      for (int j2 = 0; j2 < 4; ++j2) {
        float vv = acc[i][j2];
        if (BIAS) vv += bias[n0 + tx * 4 + j2];
        if (ACC) vv += cp[j2];
        cp[j2] = vv;
      }
    }
  }
}

// ---------------------------------------------------------------------------
// causal depthwise conv (k=4, zero left-pad) + bias + SiLU over x_in=up[:, :256]
// ---------------------------------------------------------------------------
__global__ __launch_bounds__(256) void conv_silu_kernel(
    const float* __restrict__ up, const float* __restrict__ Wc,
    const float* __restrict__ bc, float* __restrict__ xc)
{
  int row = blockIdx.x;          // b*862 + s
  int i = threadIdx.x;
  int b = row / SS, s = row - b * SS;
  float acc = bc[i];
  #pragma unroll
  for (int w2 = 0; w2 < 4; ++w2) {
    int sp = s - 3 + w2;
    if (sp >= 0) acc += up[((size_t)b * SS + sp) * 512 + i] * Wc[w2 * 256 + i];
  }
  float sg = 1.f / (1.f + __expf(-acc));
  xc[(size_t)row * II + i] = acc * sg;
}

// ---------------------------------------------------------------------------
// gate preacts: ig/fg[b,h,s] = [q,k,v] @ Wi/Wf + bias.  One wave per row.
// ---------------------------------------------------------------------------
__global__ __launch_bounds__(256) void gates_kernel(
    const float* __restrict__ q, const float* __restrict__ k, const float* __restrict__ v,
    const float* __restrict__ Wi, const float* __restrict__ bi,
    const float* __restrict__ Wf, const float* __restrict__ bfp,
    float* __restrict__ ig, float* __restrict__ fg)
{
  int row = blockIdx.x * 4 + (threadIdx.x >> 6);
  int lane = threadIdx.x & 63;
  float acc[8] = {};
  for (int j = lane; j < 768; j += 64) {
    float gv;
    if (j < 256) gv = q[(size_t)row * II + j];
    else if (j < 512) gv = k[(size_t)row * II + j - 256];
    else gv = v[(size_t)row * II + j - 512];
    float4 wi4 = *(const float4*)&Wi[j * 4];
    float4 wf4 = *(const float4*)&Wf[j * 4];
    acc[0] += gv * wi4.x; acc[1] += gv * wi4.y; acc[2] += gv * wi4.z; acc[3] += gv * wi4.w;
    acc[4] += gv * wf4.x; acc[5] += gv * wf4.y; acc[6] += gv * wf4.z; acc[7] += gv * wf4.w;
  }
  #pragma unroll
  for (int o = 0; o < 8; ++o)
    #pragma unroll
    for (int d2 = 1; d2 < 64; d2 <<= 1) acc[o] += __shfl_xor(acc[o], d2);
  int b = row / SS, s = row - b * SS;
  if (lane < 4) {
    ig[((size_t)b * NHH + lane) * SS + s] = acc[lane] + bi[lane];
  } else if (lane < 8) {
    int o = lane - 4;
    fg[((size_t)b * NHH + o) * SS + s] = acc[4 + o] + bfp[o];
  }
}

// ---------------------------------------------------------------------------
// per-(b,h) scan: cum = cumsum(logsigmoid(fg)); a = ig - cum; M = prefmax(a)
// one wave per (b,h); 14-element chunks + wave scans.
// ---------------------------------------------------------------------------
__device__ __forceinline__ float logsig(float x) {
  return fminf(x, 0.f) - log1pf(__expf(-fabsf(x)));
}

__global__ __launch_bounds__(64) void scan_kernel(
    const float* __restrict__ fg, const float* __restrict__ ig,
    float* __restrict__ cumf, float* __restrict__ aa, float* __restrict__ MMb)
{
  int bh = blockIdx.x;
  int lane = threadIdx.x;
  const float* f = fg + (size_t)bh * SS;
  const float* g = ig + (size_t)bh * SS;
  int s0 = lane * 14, s1 = s0 + 14; if (s1 > SS) s1 = SS;
  float loc = 0.f;
  for (int s = s0; s < s1; ++s) loc += logsig(f[s]);
  float v = loc;
  #pragma unroll
  for (int d = 1; d < 64; d <<= 1) { float o = __shfl_up(v, d); if (lane >= d) v += o; }
  float run = v - loc;
  float lmax = -1e30f;
  for (int s = s0; s < s1; ++s) {
    run += logsig(f[s]);
    cumf[(size_t)bh * SS + s] = run;
    float a = g[s] - run;
    aa[(size_t)bh * SS + s] = a;
    lmax = fmaxf(lmax, a);
  }
  float mv = lmax;
  #pragma unroll
  for (int d = 1; d < 64; d <<= 1) { float o = __shfl_up(mv, d); if (lane >= d) mv = fmaxf(mv, o); }
  float em = __shfl_up(mv, 1);
  if (lane == 0) em = -1e30f;
  float runm = em;
  for (int s = s0; s < s1; ++s) {
    runm = fmaxf(runm, aa[(size_t)bh * SS + s]);
    MMb[(size_t)bh * SS + s] = runm;
  }
}

// ---------------------------------------------------------------------------
// masked decay attention.  Block = (b,h, 16 t's); 4 waves x 4 t's each.
// lane = head dim d.  w[t,s] = (q_t.k_s)/8 * e^{a_s - A} * e^{A - M_t}.
// ---------------------------------------------------------------------------
__global__ __launch_bounds__(256) void attn_kernel(
    const float* __restrict__ qb, const float* __restrict__ kb, const float* __restrict__ vb,
    const float* __restrict__ cumf, const float* __restrict__ aab, const float* __restrict__ MMb,
    float* __restrict__ hb)
{
  __shared__ float ldsK[64 * 64];
  __shared__ float ldsV[64 * 64];
  __shared__ float aal[64];
  int tid = threadIdx.x;
  int lane = tid & 63, wv = tid >> 6;
  int tb = blockIdx.x, h = blockIdx.y, b = blockIdx.z;
  int t0 = tb * 16;
  int tbase = t0 + wv * 4;
  const float* cumbh = cumf + ((size_t)b * NHH + h) * SS;
  const float* aabh  = aab  + ((size_t)b * NHH + h) * SS;
  const float* Mbh   = MMb  + ((size_t)b * NHH + h) * SS;
  float qreg[4], Mt[4], ctm[4], acc[4] = {0,0,0,0}, wsum[4] = {0,0,0,0};
  #pragma unroll
  for (int j = 0; j < 4; ++j) {
    int t = tbase + j; int tc = t < SS ? t : SS - 1;
    qreg[j] = qb[((size_t)b * SS + tc) * II + h * DHH + lane] * 0.125f;
    Mt[j] = Mbh[tc]; ctm[j] = cumbh[tc];
  }
  int tmaxb = t0 + 15; if (tmaxb > SS - 1) tmaxb = SS - 1;
  int tw = tbase + 3; if (tw > SS - 1) tw = SS - 1;
  int ntiles = tmaxb / 64 + 1;
  for (int tile = 0; tile < ntiles; ++tile) {
    int s0 = tile * 64;
    for (int j = 0; j < 16; ++j) {
      int idx = tid + j * 256;
      int ss = idx >> 6, dd = idx & 63;
      int sg = s0 + ss;
      float kkv = 0.f, vvv = 0.f;
      if (sg < SS) {
        size_t base = ((size_t)b * SS + sg) * II + h * DHH + dd;
        kkv = kb[base]; vvv = vb[base];
      }
      ldsK[idx] = kkv; ldsV[idx] = vvv;
    }
    if (tid < 64) {
      int sg = s0 + tid;
      aal[tid] = (sg < SS) ? aabh[sg] : -1e30f;
    }
    __syncthreads();
    float am = aal[lane];
    #pragma unroll
    for (int d = 1; d < 64; d <<= 1) am = fmaxf(am, __shfl_xor(am, d));
    float ft[4];
    #pragma unroll
    for (int j = 0; j < 4; ++j) ft[j] = __expf(fminf(am - Mt[j], 80.f));
    int smax = tw - s0; if (smax > 63) smax = 63;
    for (int si = 0; si <= smax; ++si) {
      float e = __expf(aal[si] - am);
      float kkv = ldsK[si * 64 + lane];
      float vvv = ldsV[si * 64 + lane];
      #pragma unroll
      for (int j = 0; j < 4; ++j) {
        if (s0 + si <= tbase + j) {
          float p = qreg[j] * kkv;
          #pragma unroll
          for (int d = 1; d < 64; d <<= 1) p += __shfl_xor(p, d);
          float w = p * e * ft[j];
          acc[j] += w * vvv;
          wsum[j] += w;
        }
      }
    }
    __syncthreads();
  }
  #pragma unroll
  for (int j = 0; j < 4; ++j) {
    int t = tbase + j;
    if (t < SS) {
      float norm = fmaxf(fabsf(wsum[j]), __expf(-(ctm[j] + Mt[j])));
      hb[((size_t)b * SS + t) * II + h * DHH + lane] = acc[j] / norm;
    }
  }
}

// ---------------------------------------------------------------------------
// per-head LN (weight mh_g) + skip*xc + *silu(z), in-place on hb
// ---------------------------------------------------------------------------
__global__ __launch_bounds__(256) void mhln_kernel(
    const float* __restrict__ up, const float* __restrict__ xc,
    const float* __restrict__ mhg, const float* __restrict__ skip,
    float* __restrict__ hb)
{
  int row = blockIdx.x;
  int h = threadIdx.x >> 6, lane = threadIdx.x & 63;
  int i = h * DHH + lane;
  float hv = hb[(size_t)row * II + i];
  float s = hv, sq = hv * hv;
  #pragma unroll
  for (int d = 1; d < 64; d <<= 1) { s += __shfl_xor(s, d); sq += __shfl_xor(sq, d); }
  float mu = s * (1.f / 64.f);
  float var = sq * (1.f / 64.f) - mu * mu;
  float hn = (hv - mu) * rsqrtf(var + 1e-5f) * mhg[i];
  float z = up[(size_t)row * 512 + 256 + i];
  float sil = z / (1.f + __expf(-z));
  hb[(size_t)row * II + i] = (hn + skip[i] * xc[(size_t)row * II + i]) * sil;
}

// ---------------------------------------------------------------------------
// final: out[b,p,c] = LN(x)@Wp2^T + bp2, transposed write via LDS
// ---------------------------------------------------------------------------
__global__ __launch_bounds__(256) void final_kernel(
    const float* __restrict__ y, const float* __restrict__ Wp2,
    const float* __restrict__ bp2, float* __restrict__ out)
{
  __shared__ float yl[32 * 129];
  __shared__ float ol[96 * 32];
  int tid = threadIdx.x;
  int blk = blockIdx.x;
  int b = blk / 27, ct = blk % 27;
  int c0 = ct * 32;
  int nc = CC - c0; if (nc > 32) nc = 32;
  for (int j = 0; j < 16; ++j) {
    int idx = tid + j * 256;
    int cl = idx >> 7, d2 = idx & 127;
    yl[cl * 129 + d2] = (cl < nc) ? y[((size_t)b * CC + c0 + cl) * DD + d2] : 0.f;
  }
  __syncthreads();
  for (int j = 0; j < 12; ++j) {
    int o = tid + j * 256;
    int p = o >> 5, cl = o & 31;
    const float* wr = Wp2 + p * 128;
    float acc = bp2[p];
    for (int d2 = 0; d2 < 128; ++d2) acc += yl[cl * 129 + d2] * wr[d2];
    ol[p * 32 + cl] = acc;
  }
  __syncthreads();
  for (int j = 0; j < 12; ++j) {
    int o = tid + j * 256;
    int p = o >> 5, cl = o & 31;
    if (cl < nc) out[(size_t)b * PP * CC + (size_t)p * CC + c0 + cl] = ol[p * 32 + cl];
  }
}

// ---------------------------------------------------------------------------
extern "C" void kernel_launch(void* const* d_in, const int* in_sizes, int n_in,
                              void* d_out, int out_size, void* d_ws, size_t ws_size,
                              hipStream_t stream) {
  const float* xe   = (const float*)d_in[0];
  const float* Ws   = (const float*)d_in[4];
  const float* bs   = (const float*)d_in[5];
  const float* Wt   = (const float*)d_in[6];
  const float* bt   = (const float*)d_in[7];
  const float* Wp1  = (const float*)d_in[8];
  const float* bp1  = (const float*)d_in[9];
  const float* Wp2  = (const float*)d_in[10];
  const float* bp2  = (const float*)d_in[11];
  const float* lng  = (const float*)d_in[12];
  const float* Wup  = (const float*)d_in[13];
  const float* bup  = (const float*)d_in[14];
  const float* Wcv  = (const float*)d_in[15];
  const float* bcv  = (const float*)d_in[16];
  const float* Wq   = (const float*)d_in[17];
  const float* Wk   = (const float*)d_in[18];
  const float* Wv   = (const float*)d_in[19];
  const float* Wi   = (const float*)d_in[20];
  const float* bi   = (const float*)d_in[21];
  const float* Wf   = (const float*)d_in[22];
  const float* bf_  = (const float*)d_in[23];
  const float* mhg  = (const float*)d_in[24];
  const float* skp  = (const float*)d_in[25];
  const float* Wdn  = (const float*)d_in[26];
  const float* bdn  = (const float*)d_in[27];
  const float* pg   = (const float*)d_in[28];
  float* out = (float*)d_out;

  float* w   = (float*)d_ws;
  float* x   = w;                       // [6896,128]
  float* y   = x   + 882688;            // [6896,128]
  float* up  = y   + 882688;            // [6896,512]
  float* xc  = up  + 3530752;           // [6896,256]
  float* q   = xc  + 1765376;           // [6896,256]
  float* k   = q   + 1765376;           // [6896,256]
  float* v   = k   + 1765376;           // [6896,256]
  float* ig  = v   + 1765376;           // [8,4,862]
  float* fg  = ig  + 27584;
  float* cum = fg  + 27584;
  float* aab = cum + 27584;
  float* MMb = aab + 27584;
  float* hb  = MMb + 27584;             // [6896,256]

  head_kernel<<<864, 256, 0, stream>>>(xe, Ws, bs, Wt, bt, Wp1, bp1, x);

  for (int blk = 0; blk < 2; ++blk) {
    ln_kernel<<<1724, 256, 0, stream>>>(x, lng + blk * 128, y, BC);
    gemm_f32<false, true><<<dim3(8, 108), 256, 0, stream>>>(
        y, 128, Wup + blk * 128 * 512, 512, up, 512, bup + blk * 512, BC, 512, 128);
    conv_silu_kernel<<<6896, 256, 0, stream>>>(up, Wcv + blk * 4 * 256, bcv + blk * 256, xc);
    gemm_f32<false, false><<<dim3(4, 108), 256, 0, stream>>>(
        xc, 256, Wq + blk * 65536, 256, q, 256, nullptr, BC, 256, 256);
    gemm_f32<false, false><<<dim3(4, 108), 256, 0, stream>>>(
        xc, 256, Wk + blk * 65536, 256, k, 256, nullptr, BC, 256, 256);
    gemm_f32<false, false><<<dim3(4, 108), 256, 0, stream>>>(
        up, 512, Wv + blk * 65536, 256, v, 256, nullptr, BC, 256, 256);
    gates_kernel<<<1724, 256, 0, stream>>>(q, k, v, Wi + blk * 3072, bi + blk * 4,
                                           Wf + blk * 3072, bf_ + blk * 4, ig, fg);
    scan_kernel<<<32, 64, 0, stream>>>(fg, ig, cum, aab, MMb);
    attn_kernel<<<dim3(54, 4, 8), 256, 0, stream>>>(q, k, v, cum, aab, MMb, hb);
    mhln_kernel<<<6896, 256, 0, stream>>>(up, xc, mhg + blk * 256, skp + blk * 256, hb);
    gemm_f32<true, true><<<dim3(2, 108), 256, 0, stream>>>(
        hb, 256, Wdn + blk * 256 * 128, 128, x, 128, bdn + blk * 128, BC, 128, 256);
  }

  ln_kernel<<<1724, 256, 0, stream>>>(x, pg, y, BC);
  final_kernel<<<216, 256, 0, stream>>>(y, Wp2, bp2, out);
}

// Round 2
// 767.511 us; speedup vs baseline: 4.2504x; 4.2504x over previous
//
#include <hip/hip_runtime.h>
#include <math.h>

#define BB 8
#define LL 512
#define CC 862
#define PP 96
#define DD 128
#define II 256
#define NHH 4
#define DHH 64
#define SS 862            // mLSTM sequence length = C
#define BC (BB*CC)        // 6896 rows

// ---------------------------------------------------------------------------
// Fused series-decomp + DLinear heads + P->D projection.
// ---------------------------------------------------------------------------
__global__ __launch_bounds__(256) void head_kernel(
    const float* __restrict__ xe,
    const float* __restrict__ Ws, const float* __restrict__ bs,
    const float* __restrict__ Wt, const float* __restrict__ bt,
    const float* __restrict__ Wp1, const float* __restrict__ bp1,
    float* __restrict__ xout)
{
  __shared__ float xel[536 * 8];
  __shared__ float mml[512 * 8];
  __shared__ float x0l[8][100];
  int tid = threadIdx.x;
  int blk = blockIdx.x;
  int b = blk / 108, ct = blk % 108;
  int c0 = ct * 8;
  for (int j = 0; j < 17; ++j) {
    int idx = tid + j * 256;
    if (idx < 4288) {
      int li = idx >> 3, cl = idx & 7;
      int l = li - 12; l = l < 0 ? 0 : (l > 511 ? 511 : l);
      int c = c0 + cl; if (c > CC - 1) c = CC - 1;
      xel[idx] = xe[((size_t)b * LL + l) * CC + c];
    }
  }
  __syncthreads();
  for (int j = 0; j < 16; ++j) {
    int idx = tid + j * 256;
    int l = idx >> 3, cl = idx & 7;
    float s = 0.f;
    #pragma unroll 5
    for (int o = 0; o < 25; ++o) s += xel[(l + o) * 8 + cl];
    mml[idx] = s * (1.f / 25.f);
  }
  __syncthreads();
  for (int j = 0; j < 3; ++j) {
    int o = tid + j * 256;
    int cl = o & 7, p = o >> 3;
    const float* wsr = Ws + p * 512;
    const float* wtr = Wt + p * 512;
    float acc = bs[p] + bt[p];
    for (int l = 0; l < 512; ++l) {
      float xv = xel[(l + 12) * 8 + cl];
      float mv = mml[l * 8 + cl];
      acc += (xv - mv) * wsr[l] + mv * wtr[l];
    }
    x0l[cl][p] = acc;
  }
  __syncthreads();
  for (int j = 0; j < 4; ++j) {
    int o = tid + j * 256;
    int d = o & 127, cl = o >> 7;
    int c = c0 + cl;
    if (c < CC) {
      const float* wp = Wp1 + d * 96;
      float acc = bp1[d];
      #pragma unroll 8
      for (int p = 0; p < 96; ++p) acc += x0l[cl][p] * wp[p];
      xout[((size_t)b * CC + c) * DD + d] = acc;
    }
  }
}

// ---------------------------------------------------------------------------
// Row LayerNorm (D=128), weight-only.
// ---------------------------------------------------------------------------
__global__ __launch_bounds__(256) void ln_kernel(
    const float* __restrict__ x, const float* __restrict__ g,
    float* __restrict__ y, int nrows)
{
  int row = blockIdx.x * 4 + (threadIdx.x >> 6);
  int lane = threadIdx.x & 63;
  if (row >= nrows) return;
  const float* xr = x + (size_t)row * DD;
  float a = xr[lane], b2 = xr[lane + 64];
  float s = a + b2, sq = a * a + b2 * b2;
  #pragma unroll
  for (int d = 1; d < 64; d <<= 1) { s += __shfl_xor(s, d); sq += __shfl_xor(sq, d); }
  float mean = s * (1.f / 128.f);
  float var = sq * (1.f / 128.f) - mean * mean;
  float r = rsqrtf(var + 1e-5f);
  y[(size_t)row * DD + lane] = (a - mean) * r * g[lane];
  y[(size_t)row * DD + 64 + lane] = (b2 - mean) * r * g[64 + lane];
}

// ---------------------------------------------------------------------------
// fp32 tiled GEMM: BM=BN=64, BK=16, 256 threads, 4x4 micro-tile.
// ---------------------------------------------------------------------------
template<bool ACC, bool BIAS>
__global__ __launch_bounds__(256) void gemm_f32(
    const float* __restrict__ A, int lda,
    const float* __restrict__ Bm, int ldb,
    float* __restrict__ Cm, int ldc,
    const float* __restrict__ bias,
    int M, int N, int K)
{
  __shared__ float As[16][68];
  __shared__ float Bs[16][64];
  int tid = threadIdx.x;
  int tx = tid & 15, ty = tid >> 4;
  int m0 = blockIdx.y * 64;
  int n0 = blockIdx.x * 64;
  float acc[4][4] = {};
  for (int k0 = 0; k0 < K; k0 += 16) {
    #pragma unroll
    for (int j = 0; j < 4; ++j) {
      int idx = tid + j * 256;
      int r = idx >> 4, kk = idx & 15;
      int row = m0 + r;
      As[kk][r] = (row < M) ? A[(size_t)row * lda + k0 + kk] : 0.f;
    }
    #pragma unroll
    for (int j = 0; j < 4; ++j) {
      int idx = tid + j * 256;
      int r = idx >> 6, cc = idx & 63;
      Bs[r][cc] = Bm[(size_t)(k0 + r) * ldb + n0 + cc];
    }
    __syncthreads();
    #pragma unroll
    for (int kk = 0; kk < 16; ++kk) {
      float4 av = *(const float4*)&As[kk][ty * 4];
      float4 bv = *(const float4*)&Bs[kk][tx * 4];
      float a0[4] = {av.x, av.y, av.z, av.w};
      float b0[4] = {bv.x, bv.y, bv.z, bv.w};
      #pragma unroll
      for (int i = 0; i < 4; ++i)
        #pragma unroll
        for (int j2 = 0; j2 < 4; ++j2) acc[i][j2] += a0[i] * b0[j2];
    }
    __syncthreads();
  }
  #pragma unroll
  for (int i = 0; i < 4; ++i) {
    int row = m0 + ty * 4 + i;
    if (row < M) {
      float* cp = Cm + (size_t)row * ldc + n0 + tx * 4;
      #pragma unroll
      for (int j2 = 0; j2 < 4; ++j2) {
        float vv = acc[i][j2];
        if (BIAS) vv += bias[n0 + tx * 4 + j2];
        if (ACC) vv += cp[j2];
        cp[j2] = vv;
      }
    }
  }
}

// ---------------------------------------------------------------------------
// causal depthwise conv (k=4) + bias + SiLU
// ---------------------------------------------------------------------------
__global__ __launch_bounds__(256) void conv_silu_kernel(
    const float* __restrict__ up, const float* __restrict__ Wc,
    const float* __restrict__ bc, float* __restrict__ xc)
{
  int row = blockIdx.x;
  int i = threadIdx.x;
  int b = row / SS, s = row - b * SS;
  float acc = bc[i];
  #pragma unroll
  for (int w2 = 0; w2 < 4; ++w2) {
    int sp = s - 3 + w2;
    if (sp >= 0) acc += up[((size_t)b * SS + sp) * 512 + i] * Wc[w2 * 256 + i];
  }
  float sg = 1.f / (1.f + __expf(-acc));
  xc[(size_t)row * II + i] = acc * sg;
}

// ---------------------------------------------------------------------------
// gate preacts
// ---------------------------------------------------------------------------
__global__ __launch_bounds__(256) void gates_kernel(
    const float* __restrict__ q, const float* __restrict__ k, const float* __restrict__ v,
    const float* __restrict__ Wi, const float* __restrict__ bi,
    const float* __restrict__ Wf, const float* __restrict__ bfp,
    float* __restrict__ ig, float* __restrict__ fg)
{
  int row = blockIdx.x * 4 + (threadIdx.x >> 6);
  int lane = threadIdx.x & 63;
  float acc[8] = {};
  for (int j = lane; j < 768; j += 64) {
    float gv;
    if (j < 256) gv = q[(size_t)row * II + j];
    else if (j < 512) gv = k[(size_t)row * II + j - 256];
    else gv = v[(size_t)row * II + j - 512];
    float4 wi4 = *(const float4*)&Wi[j * 4];
    float4 wf4 = *(const float4*)&Wf[j * 4];
    acc[0] += gv * wi4.x; acc[1] += gv * wi4.y; acc[2] += gv * wi4.z; acc[3] += gv * wi4.w;
    acc[4] += gv * wf4.x; acc[5] += gv * wf4.y; acc[6] += gv * wf4.z; acc[7] += gv * wf4.w;
  }
  #pragma unroll
  for (int o = 0; o < 8; ++o)
    #pragma unroll
    for (int d2 = 1; d2 < 64; d2 <<= 1) acc[o] += __shfl_xor(acc[o], d2);
  int b = row / SS, s = row - b * SS;
  if (lane < 4) {
    ig[((size_t)b * NHH + lane) * SS + s] = acc[lane] + bi[lane];
  } else if (lane < 8) {
    int o = lane - 4;
    fg[((size_t)b * NHH + o) * SS + s] = acc[4 + o] + bfp[o];
  }
}

// ---------------------------------------------------------------------------
// per-(b,h) scan
// ---------------------------------------------------------------------------
__device__ __forceinline__ float logsig(float x) {
  return fminf(x, 0.f) - log1pf(__expf(-fabsf(x)));
}

__global__ __launch_bounds__(64) void scan_kernel(
    const float* __restrict__ fg, const float* __restrict__ ig,
    float* __restrict__ cumf, float* __restrict__ aa, float* __restrict__ MMb)
{
  int bh = blockIdx.x;
  int lane = threadIdx.x;
  const float* f = fg + (size_t)bh * SS;
  const float* g = ig + (size_t)bh * SS;
  int s0 = lane * 14, s1 = s0 + 14; if (s1 > SS) s1 = SS;
  float loc = 0.f;
  for (int s = s0; s < s1; ++s) loc += logsig(f[s]);
  float v = loc;
  #pragma unroll
  for (int d = 1; d < 64; d <<= 1) { float o = __shfl_up(v, d); if (lane >= d) v += o; }
  float run = v - loc;
  float lmax = -1e30f;
  for (int s = s0; s < s1; ++s) {
    run += logsig(f[s]);
    cumf[(size_t)bh * SS + s] = run;
    float a = g[s] - run;
    aa[(size_t)bh * SS + s] = a;
    lmax = fmaxf(lmax, a);
  }
  float mv = lmax;
  #pragma unroll
  for (int d = 1; d < 64; d <<= 1) { float o = __shfl_up(mv, d); if (lane >= d) mv = fmaxf(mv, o); }
  float em = __shfl_up(mv, 1);
  if (lane == 0) em = -1e30f;
  float runm = em;
  for (int s = s0; s < s1; ++s) {
    runm = fmaxf(runm, aa[(size_t)bh * SS + s]);
    MMb[(size_t)bh * SS + s] = runm;
  }
}

// ---------------------------------------------------------------------------
// masked decay attention — dual-GEMM form.
// Block = (b,h, 64 t's). 256 threads, 16x16, 4x4 micro-tile. s-tiles of 64.
// Phase1: P = Qs.K^T (register tile); decay+mask in regs; W -> LDS (transposed)
// Phase2: acc += W^T-form GEMM with V.  wsum via 16-lane shuffle reduce.
// ---------------------------------------------------------------------------
__global__ __launch_bounds__(256) void attn_kernel(
    const float* __restrict__ qb, const float* __restrict__ kb, const float* __restrict__ vb,
    const float* __restrict__ cumf, const float* __restrict__ aab, const float* __restrict__ MMb,
    float* __restrict__ hb)
{
  __shared__ float QT[64 * 68];   // [d][t]
  __shared__ float KT[64 * 68];   // [d][s]
  __shared__ float Vs[64 * 68];   // [s][d]
  __shared__ float Wt[64 * 68];   // [s][t]
  __shared__ float a_lds[64];
  int tid = threadIdx.x;
  int tx = tid & 15, ty = tid >> 4;
  int lane = tid & 63;
  int tb = blockIdx.x, h = blockIdx.y, b = blockIdx.z;
  int t0 = tb * 64;
  const float* aabh  = aab  + ((size_t)b * NHH + h) * SS;
  const float* Mbh   = MMb  + ((size_t)b * NHH + h) * SS;
  const float* cumbh = cumf + ((size_t)b * NHH + h) * SS;

  // load QT (transposed, pre-scaled by DH^-0.5)
  for (int it = 0; it < 4; ++it) {
    int idx = tid + it * 256;
    int s = idx >> 4, d0 = (idx & 15) * 4;
    int t = t0 + s;
    float4 qv = make_float4(0.f, 0.f, 0.f, 0.f);
    if (t < SS) qv = *(const float4*)&qb[((size_t)b * SS + t) * II + h * 64 + d0];
    QT[(d0 + 0) * 68 + s] = qv.x * 0.125f;
    QT[(d0 + 1) * 68 + s] = qv.y * 0.125f;
    QT[(d0 + 2) * 68 + s] = qv.z * 0.125f;
    QT[(d0 + 3) * 68 + s] = qv.w * 0.125f;
  }
  float Mt[4], nfloor[4];
  #pragma unroll
  for (int i = 0; i < 4; ++i) {
    int t = t0 + ty * 4 + i; int tc = t < SS ? t : SS - 1;
    Mt[i] = Mbh[tc];
    nfloor[i] = __expf(-(cumbh[tc] + Mt[i]));
  }
  float acc[4][4] = {};
  float wsum[4] = {0.f, 0.f, 0.f, 0.f};
  int tlast = t0 + 63; if (tlast > SS - 1) tlast = SS - 1;
  int ntiles = tlast / 64 + 1;

  for (int st = 0; st < ntiles; ++st) {
    int s0 = st * 64;
    __syncthreads();
    for (int it = 0; it < 4; ++it) {
      int idx = tid + it * 256;
      int s = idx >> 4, d0 = (idx & 15) * 4;
      int sg = s0 + s;
      float4 kv = make_float4(0.f, 0.f, 0.f, 0.f);
      float4 vv = make_float4(0.f, 0.f, 0.f, 0.f);
      if (sg < SS) {
        size_t base = ((size_t)b * SS + sg) * II + h * 64 + d0;
        kv = *(const float4*)&kb[base];
        vv = *(const float4*)&vb[base];
      }
      KT[(d0 + 0) * 68 + s] = kv.x;
      KT[(d0 + 1) * 68 + s] = kv.y;
      KT[(d0 + 2) * 68 + s] = kv.z;
      KT[(d0 + 3) * 68 + s] = kv.w;
      *(float4*)&Vs[s * 68 + d0] = vv;
    }
    if (tid < 64) {
      int sg = s0 + tid;
      a_lds[tid] = (sg < SS) ? aabh[sg] : -1e30f;
    }
    __syncthreads();
    // tile max of a
    float am = a_lds[lane];
    #pragma unroll
    for (int dd = 1; dd < 64; dd <<= 1) am = fmaxf(am, __shfl_xor(am, dd));
    // phase 1: P[t-frag][s-frag]
    float p[4][4] = {};
    #pragma unroll 8
    for (int d = 0; d < 64; ++d) {
      float4 av = *(const float4*)&QT[d * 68 + ty * 4];
      float4 bv = *(const float4*)&KT[d * 68 + tx * 4];
      float a0[4] = {av.x, av.y, av.z, av.w};
      float b0[4] = {bv.x, bv.y, bv.z, bv.w};
      #pragma unroll
      for (int i = 0; i < 4; ++i)
        #pragma unroll
        for (int j = 0; j < 4; ++j) p[i][j] += a0[i] * b0[j];
    }
    // decay + mask in registers
    float ee[4], ft[4];
    #pragma unroll
    for (int j = 0; j < 4; ++j) ee[j] = __expf(a_lds[tx * 4 + j] - am);
    #pragma unroll
    for (int i = 0; i < 4; ++i) ft[i] = __expf(fminf(am - Mt[i], 80.f));
    float w[4][4];
    #pragma unroll
    for (int i = 0; i < 4; ++i) {
      int t = t0 + ty * 4 + i;
      float psum = 0.f;
      #pragma unroll
      for (int j = 0; j < 4; ++j) {
        int s = s0 + tx * 4 + j;
        float wv = (s <= t) ? p[i][j] * ee[j] * ft[i] : 0.f;
        w[i][j] = wv;
        psum += wv;
      }
      psum += __shfl_xor(psum, 1);
      psum += __shfl_xor(psum, 2);
      psum += __shfl_xor(psum, 4);
      psum += __shfl_xor(psum, 8);
      wsum[i] += psum;
    }
    // stage W transposed: Wt[s][t]
    #pragma unroll
    for (int j = 0; j < 4; ++j) {
      float4 wv4 = make_float4(w[0][j], w[1][j], w[2][j], w[3][j]);
      *(float4*)&Wt[(tx * 4 + j) * 68 + ty * 4] = wv4;
    }
    __syncthreads();
    // phase 2: acc[t][d] += sum_s Wt[s][t] * Vs[s][d]
    #pragma unroll 8
    for (int s = 0; s < 64; ++s) {
      float4 av = *(const float4*)&Wt[s * 68 + ty * 4];
      float4 bv = *(const float4*)&Vs[s * 68 + tx * 4];
      float a0[4] = {av.x, av.y, av.z, av.w};
      float b0[4] = {bv.x, bv.y, bv.z, bv.w};
      #pragma unroll
      for (int i = 0; i < 4; ++i)
        #pragma unroll
        for (int j = 0; j < 4; ++j) acc[i][j] += a0[i] * b0[j];
    }
  }
  #pragma unroll
  for (int i = 0; i < 4; ++i) {
    int t = t0 + ty * 4 + i;
    if (t < SS) {
      float rn = 1.f / fmaxf(fabsf(wsum[i]), nfloor[i]);
      float4 o = make_float4(acc[i][0] * rn, acc[i][1] * rn, acc[i][2] * rn, acc[i][3] * rn);
      *(float4*)&hb[((size_t)b * SS + t) * II + h * 64 + tx * 4] = o;
    }
  }
}

// ---------------------------------------------------------------------------
// per-head LN + skip*xc + *silu(z)
// ---------------------------------------------------------------------------
__global__ __launch_bounds__(256) void mhln_kernel(
    const float* __restrict__ up, const float* __restrict__ xc,
    const float* __restrict__ mhg, const float* __restrict__ skip,
    float* __restrict__ hb)
{
  int row = blockIdx.x;
  int h = threadIdx.x >> 6, lane = threadIdx.x & 63;
  int i = h * DHH + lane;
  float hv = hb[(size_t)row * II + i];
  float s = hv, sq = hv * hv;
  #pragma unroll
  for (int d = 1; d < 64; d <<= 1) { s += __shfl_xor(s, d); sq += __shfl_xor(sq, d); }
  float mu = s * (1.f / 64.f);
  float var = sq * (1.f / 64.f) - mu * mu;
  float hn = (hv - mu) * rsqrtf(var + 1e-5f) * mhg[i];
  float z = up[(size_t)row * 512 + 256 + i];
  float sil = z / (1.f + __expf(-z));
  hb[(size_t)row * II + i] = (hn + skip[i] * xc[(size_t)row * II + i]) * sil;
}

// ---------------------------------------------------------------------------
// final: out[b,p,c] = LN(x)@Wp2^T + bp2
// ---------------------------------------------------------------------------
__global__ __launch_bounds__(256) void final_kernel(
    const float* __restrict__ y, const float* __restrict__ Wp2,
    const float* __restrict__ bp2, float* __restrict__ out)
{
  __shared__ float yl[32 * 129];
  __shared__ float ol[96 * 32];
  int tid = threadIdx.x;
  int blk = blockIdx.x;
  int b = blk / 27, ct = blk % 27;
  int c0 = ct * 32;
  int nc = CC - c0; if (nc > 32) nc = 32;
  for (int j = 0; j < 16; ++j) {
    int idx = tid + j * 256;
    int cl = idx >> 7, d2 = idx & 127;
    yl[cl * 129 + d2] = (cl < nc) ? y[((size_t)b * CC + c0 + cl) * DD + d2] : 0.f;
  }
  __syncthreads();
  for (int j = 0; j < 12; ++j) {
    int o = tid + j * 256;
    int p = o >> 5, cl = o & 31;
    const float* wr = Wp2 + p * 128;
    float acc = bp2[p];
    for (int d2 = 0; d2 < 128; ++d2) acc += yl[cl * 129 + d2] * wr[d2];
    ol[p * 32 + cl] = acc;
  }
  __syncthreads();
  for (int j = 0; j < 12; ++j) {
    int o = tid + j * 256;
    int p = o >> 5, cl = o & 31;
    if (cl < nc) out[(size_t)b * PP * CC + (size_t)p * CC + c0 + cl] = ol[p * 32 + cl];
  }
}

// ---------------------------------------------------------------------------
extern "C" void kernel_launch(void* const* d_in, const int* in_sizes, int n_in,
                              void* d_out, int out_size, void* d_ws, size_t ws_size,
                              hipStream_t stream) {
  const float* xe   = (const float*)d_in[0];
  const float* Ws   = (const float*)d_in[4];
  const float* bs   = (const float*)d_in[5];
  const float* Wt_  = (const float*)d_in[6];
  const float* bt   = (const float*)d_in[7];
  const float* Wp1  = (const float*)d_in[8];
  const float* bp1  = (const float*)d_in[9];
  const float* Wp2  = (const float*)d_in[10];
  const float* bp2  = (const float*)d_in[11];
  const float* lng  = (const float*)d_in[12];
  const float* Wup  = (const float*)d_in[13];
  const float* bup  = (const float*)d_in[14];
  const float* Wcv  = (const float*)d_in[15];
  const float* bcv  = (const float*)d_in[16];
  const float* Wq   = (const float*)d_in[17];
  const float* Wk   = (const float*)d_in[18];
  const float* Wv   = (const float*)d_in[19];
  const float* Wi   = (const float*)d_in[20];
  const float* bi   = (const float*)d_in[21];
  const float* Wf   = (const float*)d_in[22];
  const float* bf_  = (const float*)d_in[23];
  const float* mhg  = (const float*)d_in[24];
  const float* skp  = (const float*)d_in[25];
  const float* Wdn  = (const float*)d_in[26];
  const float* bdn  = (const float*)d_in[27];
  const float* pg   = (const float*)d_in[28];
  float* out = (float*)d_out;

  float* w   = (float*)d_ws;
  float* x   = w;                       // [6896,128]
  float* y   = x   + 882688;            // [6896,128]
  float* up  = y   + 882688;            // [6896,512]
  float* xc  = up  + 3530752;           // [6896,256]
  float* q   = xc  + 1765376;           // [6896,256]
  float* k   = q   + 1765376;           // [6896,256]
  float* v   = k   + 1765376;           // [6896,256]
  float* ig  = v   + 1765376;           // [8,4,862]
  float* fg  = ig  + 27584;
  float* cum = fg  + 27584;
  float* aab = cum + 27584;
  float* MMb = aab + 27584;
  float* hb  = MMb + 27584;             // [6896,256]

  head_kernel<<<864, 256, 0, stream>>>(xe, Ws, bs, Wt_, bt, Wp1, bp1, x);

  for (int blk = 0; blk < 2; ++blk) {
    ln_kernel<<<1724, 256, 0, stream>>>(x, lng + blk * 128, y, BC);
    gemm_f32<false, true><<<dim3(8, 108), 256, 0, stream>>>(
        y, 128, Wup + blk * 128 * 512, 512, up, 512, bup + blk * 512, BC, 512, 128);
    conv_silu_kernel<<<6896, 256, 0, stream>>>(up, Wcv + blk * 4 * 256, bcv + blk * 256, xc);
    gemm_f32<false, false><<<dim3(4, 108), 256, 0, stream>>>(
        xc, 256, Wq + blk * 65536, 256, q, 256, nullptr, BC, 256, 256);
    gemm_f32<false, false><<<dim3(4, 108), 256, 0, stream>>>(
        xc, 256, Wk + blk * 65536, 256, k, 256, nullptr, BC, 256, 256);
    gemm_f32<false, false><<<dim3(4, 108), 256, 0, stream>>>(
        up, 512, Wv + blk * 65536, 256, v, 256, nullptr, BC, 256, 256);
    gates_kernel<<<1724, 256, 0, stream>>>(q, k, v, Wi + blk * 3072, bi + blk * 4,
                                           Wf + blk * 3072, bf_ + blk * 4, ig, fg);
    scan_kernel<<<32, 64, 0, stream>>>(fg, ig, cum, aab, MMb);
    attn_kernel<<<dim3(14, 4, 8), 256, 0, stream>>>(q, k, v, cum, aab, MMb, hb);
    mhln_kernel<<<6896, 256, 0, stream>>>(up, xc, mhg + blk * 256, skp + blk * 256, hb);
    gemm_f32<true, true><<<dim3(2, 108), 256, 0, stream>>>(
        hb, 256, Wdn + blk * 256 * 128, 128, x, 128, bdn + blk * 128, BC, 128, 256);
  }

  ln_kernel<<<1724, 256, 0, stream>>>(x, pg, y, BC);
  final_kernel<<<216, 256, 0, stream>>>(y, Wp2, bp2, out);
}

// Round 3
// 745.771 us; speedup vs baseline: 4.3743x; 1.0292x over previous
//
#include <hip/hip_runtime.h>
#include <math.h>

#define BB 8
#define LL 512
#define CC 862
#define PP 96
#define DD 128
#define II 256
#define NHH 4
#define DHH 64
#define SS 862            // mLSTM sequence length = C
#define BC (BB*CC)        // 6896 rows

// ---------------------------------------------------------------------------
// Fused series-decomp + DLinear heads + P->D projection.
// LDS layout [cl][l] so the l-loop vectorizes to float4.
// ---------------------------------------------------------------------------
__global__ __launch_bounds__(256) void head_kernel(
    const float* __restrict__ xe,
    const float* __restrict__ Ws, const float* __restrict__ bs,
    const float* __restrict__ Wt, const float* __restrict__ bt,
    const float* __restrict__ Wp1, const float* __restrict__ bp1,
    float* __restrict__ xout)
{
  __shared__ float xel[8][548];   // l' = 0..535  (actual l = clamp(l'-12))
  __shared__ float mml[8][520];   // mm[cl][l], l = 0..511
  __shared__ float x0l[8][100];
  int tid = threadIdx.x;
  int blk = blockIdx.x;
  int b = blk / 108, ct = blk % 108;
  int c0 = ct * 8;
  for (int j = 0; j < 17; ++j) {
    int idx = tid + j * 256;
    if (idx < 4288) {
      int li = idx >> 3, cl = idx & 7;
      int l = li - 12; l = l < 0 ? 0 : (l > 511 ? 511 : l);
      int c = c0 + cl; if (c > CC - 1) c = CC - 1;
      xel[cl][li] = xe[((size_t)b * LL + l) * CC + c];
    }
  }
  __syncthreads();
  // moving average via sliding window: thread -> (cl, 16 consecutive l)
  {
    int cl = tid & 7;
    int l0 = (tid >> 3) * 16;
    float win = 0.f;
    #pragma unroll 5
    for (int o = 0; o < 25; ++o) win += xel[cl][l0 + o];
    mml[cl][l0] = win * (1.f / 25.f);
    for (int i = 1; i < 16; ++i) {
      win += xel[cl][l0 + 24 + i] - xel[cl][l0 + i - 1];
      mml[cl][l0 + i] = win * (1.f / 25.f);
    }
  }
  __syncthreads();
  // x0[c][p] = sum_l (xe-mm)*Ws + mm*Wt  (float4 over l)
  for (int j = 0; j < 3; ++j) {
    int o = tid + j * 256;
    int cl = o & 7, p = o >> 3;
    const float* wsr = Ws + p * 512;
    const float* wtr = Wt + p * 512;
    float acc = bs[p] + bt[p];
    #pragma unroll 4
    for (int l0 = 0; l0 < 512; l0 += 4) {
      float4 xv = *(const float4*)&xel[cl][12 + l0];
      float4 mv = *(const float4*)&mml[cl][l0];
      float4 ws4 = *(const float4*)&wsr[l0];
      float4 wt4 = *(const float4*)&wtr[l0];
      acc += (xv.x - mv.x) * ws4.x + mv.x * wt4.x;
      acc += (xv.y - mv.y) * ws4.y + mv.y * wt4.y;
      acc += (xv.z - mv.z) * ws4.z + mv.z * wt4.z;
      acc += (xv.w - mv.w) * ws4.w + mv.w * wt4.w;
    }
    x0l[cl][p] = acc;
  }
  __syncthreads();
  for (int j = 0; j < 4; ++j) {
    int o = tid + j * 256;
    int d = o & 127, cl = o >> 7;
    int c = c0 + cl;
    if (c < CC) {
      const float* wp = Wp1 + d * 96;
      float acc = bp1[d];
      #pragma unroll 8
      for (int p = 0; p < 96; ++p) acc += x0l[cl][p] * wp[p];
      xout[((size_t)b * CC + c) * DD + d] = acc;
    }
  }
}

// ---------------------------------------------------------------------------
// Row LayerNorm (D=128), weight-only.
// ---------------------------------------------------------------------------
__global__ __launch_bounds__(256) void ln_kernel(
    const float* __restrict__ x, const float* __restrict__ g,
    float* __restrict__ y, int nrows)
{
  int row = blockIdx.x * 4 + (threadIdx.x >> 6);
  int lane = threadIdx.x & 63;
  if (row >= nrows) return;
  const float* xr = x + (size_t)row * DD;
  float a = xr[lane], b2 = xr[lane + 64];
  float s = a + b2, sq = a * a + b2 * b2;
  #pragma unroll
  for (int d = 1; d < 64; d <<= 1) { s += __shfl_xor(s, d); sq += __shfl_xor(sq, d); }
  float mean = s * (1.f / 128.f);
  float var = sq * (1.f / 128.f) - mean * mean;
  float r = rsqrtf(var + 1e-5f);
  y[(size_t)row * DD + lane] = (a - mean) * r * g[lane];
  y[(size_t)row * DD + 64 + lane] = (b2 - mean) * r * g[64 + lane];
}

// ---------------------------------------------------------------------------
// fp32 tiled GEMM: BM=BN=64, BK=16, 256 threads, 4x4 micro-tile.
// ---------------------------------------------------------------------------
template<bool ACC, bool BIAS>
__global__ __launch_bounds__(256) void gemm_f32(
    const float* __restrict__ A, int lda,
    const float* __restrict__ Bm, int ldb,
    float* __restrict__ Cm, int ldc,
    const float* __restrict__ bias,
    int M, int N, int K)
{
  __shared__ float As[16][68];
  __shared__ float Bs[16][64];
  int tid = threadIdx.x;
  int tx = tid & 15, ty = tid >> 4;
  int m0 = blockIdx.y * 64;
  int n0 = blockIdx.x * 64;
  float acc[4][4] = {};
  for (int k0 = 0; k0 < K; k0 += 16) {
    #pragma unroll
    for (int j = 0; j < 4; ++j) {
      int idx = tid + j * 256;
      int r = idx >> 4, kk = idx & 15;
      int row = m0 + r;
      As[kk][r] = (row < M) ? A[(size_t)row * lda + k0 + kk] : 0.f;
    }
    #pragma unroll
    for (int j = 0; j < 4; ++j) {
      int idx = tid + j * 256;
      int r = idx >> 6, cc = idx & 63;
      Bs[r][cc] = Bm[(size_t)(k0 + r) * ldb + n0 + cc];
    }
    __syncthreads();
    #pragma unroll
    for (int kk = 0; kk < 16; ++kk) {
      float4 av = *(const float4*)&As[kk][ty * 4];
      float4 bv = *(const float4*)&Bs[kk][tx * 4];
      float a0[4] = {av.x, av.y, av.z, av.w};
      float b0[4] = {bv.x, bv.y, bv.z, bv.w};
      #pragma unroll
      for (int i = 0; i < 4; ++i)
        #pragma unroll
        for (int j2 = 0; j2 < 4; ++j2) acc[i][j2] += a0[i] * b0[j2];
    }
    __syncthreads();
  }
  #pragma unroll
  for (int i = 0; i < 4; ++i) {
    int row = m0 + ty * 4 + i;
    if (row < M) {
      float* cp = Cm + (size_t)row * ldc + n0 + tx * 4;
      #pragma unroll
      for (int j2 = 0; j2 < 4; ++j2) {
        float vv = acc[i][j2];
        if (BIAS) vv += bias[n0 + tx * 4 + j2];
        if (ACC) vv += cp[j2];
        cp[j2] = vv;
      }
    }
  }
}

// ---------------------------------------------------------------------------
// causal depthwise conv (k=4) + bias + SiLU
// ---------------------------------------------------------------------------
__global__ __launch_bounds__(256) void conv_silu_kernel(
    const float* __restrict__ up, const float* __restrict__ Wc,
    const float* __restrict__ bc, float* __restrict__ xc)
{
  int row = blockIdx.x;
  int i = threadIdx.x;
  int b = row / SS, s = row - b * SS;
  float acc = bc[i];
  #pragma unroll
  for (int w2 = 0; w2 < 4; ++w2) {
    int sp = s - 3 + w2;
    if (sp >= 0) acc += up[((size_t)b * SS + sp) * 512 + i] * Wc[w2 * 256 + i];
  }
  float sg = 1.f / (1.f + __expf(-acc));
  xc[(size_t)row * II + i] = acc * sg;
}

// ---------------------------------------------------------------------------
// gate preacts
// ---------------------------------------------------------------------------
__global__ __launch_bounds__(256) void gates_kernel(
    const float* __restrict__ q, const float* __restrict__ k, const float* __restrict__ v,
    const float* __restrict__ Wi, const float* __restrict__ bi,
    const float* __restrict__ Wf, const float* __restrict__ bfp,
    float* __restrict__ ig, float* __restrict__ fg)
{
  int row = blockIdx.x * 4 + (threadIdx.x >> 6);
  int lane = threadIdx.x & 63;
  float acc[8] = {};
  for (int j = lane; j < 768; j += 64) {
    float gv;
    if (j < 256) gv = q[(size_t)row * II + j];
    else if (j < 512) gv = k[(size_t)row * II + j - 256];
    else gv = v[(size_t)row * II + j - 512];
    float4 wi4 = *(const float4*)&Wi[j * 4];
    float4 wf4 = *(const float4*)&Wf[j * 4];
    acc[0] += gv * wi4.x; acc[1] += gv * wi4.y; acc[2] += gv * wi4.z; acc[3] += gv * wi4.w;
    acc[4] += gv * wf4.x; acc[5] += gv * wf4.y; acc[6] += gv * wf4.z; acc[7] += gv * wf4.w;
  }
  #pragma unroll
  for (int o = 0; o < 8; ++o)
    #pragma unroll
    for (int d2 = 1; d2 < 64; d2 <<= 1) acc[o] += __shfl_xor(acc[o], d2);
  int b = row / SS, s = row - b * SS;
  if (lane < 4) {
    ig[((size_t)b * NHH + lane) * SS + s] = acc[lane] + bi[lane];
  } else if (lane < 8) {
    int o = lane - 4;
    fg[((size_t)b * NHH + o) * SS + s] = acc[4 + o] + bfp[o];
  }
}

// ---------------------------------------------------------------------------
// per-(b,h) scan
// ---------------------------------------------------------------------------
__device__ __forceinline__ float logsig(float x) {
  return fminf(x, 0.f) - log1pf(__expf(-fabsf(x)));
}

__global__ __launch_bounds__(64) void scan_kernel(
    const float* __restrict__ fg, const float* __restrict__ ig,
    float* __restrict__ cumf, float* __restrict__ aa, float* __restrict__ MMb)
{
  int bh = blockIdx.x;
  int lane = threadIdx.x;
  const float* f = fg + (size_t)bh * SS;
  const float* g = ig + (size_t)bh * SS;
  int s0 = lane * 14, s1 = s0 + 14; if (s1 > SS) s1 = SS;
  float loc = 0.f;
  for (int s = s0; s < s1; ++s) loc += logsig(f[s]);
  float v = loc;
  #pragma unroll
  for (int d = 1; d < 64; d <<= 1) { float o = __shfl_up(v, d); if (lane >= d) v += o; }
  float run = v - loc;
  float lmax = -1e30f;
  for (int s = s0; s < s1; ++s) {
    run += logsig(f[s]);
    cumf[(size_t)bh * SS + s] = run;
    float a = g[s] - run;
    aa[(size_t)bh * SS + s] = a;
    lmax = fmaxf(lmax, a);
  }
  float mv = lmax;
  #pragma unroll
  for (int d = 1; d < 64; d <<= 1) { float o = __shfl_up(mv, d); if (lane >= d) mv = fmaxf(mv, o); }
  float em = __shfl_up(mv, 1);
  if (lane == 0) em = -1e30f;
  float runm = em;
  for (int s = s0; s < s1; ++s) {
    runm = fmaxf(runm, aa[(size_t)bh * SS + s]);
    MMb[(size_t)bh * SS + s] = runm;
  }
}

// ---------------------------------------------------------------------------
// masked decay attention — dual-GEMM form, descending-work dispatch order,
// XOR bank swizzle on transposed LDS tiles.
// ---------------------------------------------------------------------------
#define SW(r) ((((r) >> 2) & 7) << 2)

__global__ __launch_bounds__(256) void attn_kernel(
    const float* __restrict__ qb, const float* __restrict__ kb, const float* __restrict__ vb,
    const float* __restrict__ cumf, const float* __restrict__ aab, const float* __restrict__ MMb,
    float* __restrict__ hb)
{
  __shared__ float QT[64 * 68];   // [d][t^swz]
  __shared__ float KT[64 * 68];   // [d][s^swz]
  __shared__ float Vs[64 * 68];   // [s][d]
  __shared__ float Wt[64 * 68];   // [s][t^swz]
  __shared__ float a_lds[64];
  int tid = threadIdx.x;
  int tx = tid & 15, ty = tid >> 4;
  int lane = tid & 63;
  int tb = 13 - blockIdx.x;       // heaviest blocks dispatch first
  int h = blockIdx.y, b = blockIdx.z;
  int t0 = tb * 64;
  const float* aabh  = aab  + ((size_t)b * NHH + h) * SS;
  const float* Mbh   = MMb  + ((size_t)b * NHH + h) * SS;
  const float* cumbh = cumf + ((size_t)b * NHH + h) * SS;

  // load QT (transposed+swizzled, pre-scaled by DH^-0.5)
  for (int it = 0; it < 4; ++it) {
    int idx = tid + it * 256;
    int s = idx >> 4, d0 = (idx & 15) * 4;
    int t = t0 + s;
    float4 qv = make_float4(0.f, 0.f, 0.f, 0.f);
    if (t < SS) qv = *(const float4*)&qb[((size_t)b * SS + t) * II + h * 64 + d0];
    int sw = s ^ SW(d0);
    QT[(d0 + 0) * 68 + sw] = qv.x * 0.125f;
    QT[(d0 + 1) * 68 + sw] = qv.y * 0.125f;
    QT[(d0 + 2) * 68 + sw] = qv.z * 0.125f;
    QT[(d0 + 3) * 68 + sw] = qv.w * 0.125f;
  }
  float Mt[4], nfloor[4];
  #pragma unroll
  for (int i = 0; i < 4; ++i) {
    int t = t0 + ty * 4 + i; int tc = t < SS ? t : SS - 1;
    Mt[i] = Mbh[tc];
    nfloor[i] = __expf(-(cumbh[tc] + Mt[i]));
  }
  float acc[4][4] = {};
  float wsum[4] = {0.f, 0.f, 0.f, 0.f};
  int tlast = t0 + 63; if (tlast > SS - 1) tlast = SS - 1;
  int ntiles = tlast / 64 + 1;

  for (int st = 0; st < ntiles; ++st) {
    int s0 = st * 64;
    __syncthreads();
    for (int it = 0; it < 4; ++it) {
      int idx = tid + it * 256;
      int s = idx >> 4, d0 = (idx & 15) * 4;
      int sg = s0 + s;
      float4 kv = make_float4(0.f, 0.f, 0.f, 0.f);
      float4 vv = make_float4(0.f, 0.f, 0.f, 0.f);
      if (sg < SS) {
        size_t base = ((size_t)b * SS + sg) * II + h * 64 + d0;
        kv = *(const float4*)&kb[base];
        vv = *(const float4*)&vb[base];
      }
      int sw = s ^ SW(d0);
      KT[(d0 + 0) * 68 + sw] = kv.x;
      KT[(d0 + 1) * 68 + sw] = kv.y;
      KT[(d0 + 2) * 68 + sw] = kv.z;
      KT[(d0 + 3) * 68 + sw] = kv.w;
      *(float4*)&Vs[s * 68 + d0] = vv;
    }
    if (tid < 64) {
      int sg = s0 + tid;
      a_lds[tid] = (sg < SS) ? aabh[sg] : -1e30f;
    }
    __syncthreads();
    // tile max of a
    float am = a_lds[lane];
    #pragma unroll
    for (int dd = 1; dd < 64; dd <<= 1) am = fmaxf(am, __shfl_xor(am, dd));
    // phase 1: P[t-frag][s-frag]
    float p[4][4] = {};
    #pragma unroll 8
    for (int d = 0; d < 64; ++d) {
      float4 av = *(const float4*)&QT[d * 68 + ((ty * 4) ^ SW(d))];
      float4 bv = *(const float4*)&KT[d * 68 + ((tx * 4) ^ SW(d))];
      float a0[4] = {av.x, av.y, av.z, av.w};
      float b0[4] = {bv.x, bv.y, bv.z, bv.w};
      #pragma unroll
      for (int i = 0; i < 4; ++i)
        #pragma unroll
        for (int j = 0; j < 4; ++j) p[i][j] += a0[i] * b0[j];
    }
    // decay + mask in registers
    float ee[4], ft[4];
    #pragma unroll
    for (int j = 0; j < 4; ++j) ee[j] = __expf(a_lds[tx * 4 + j] - am);
    #pragma unroll
    for (int i = 0; i < 4; ++i) ft[i] = __expf(fminf(am - Mt[i], 80.f));
    float w[4][4];
    #pragma unroll
    for (int i = 0; i < 4; ++i) {
      int t = t0 + ty * 4 + i;
      float psum = 0.f;
      #pragma unroll
      for (int j = 0; j < 4; ++j) {
        int s = s0 + tx * 4 + j;
        float wv = (s <= t) ? p[i][j] * ee[j] * ft[i] : 0.f;
        w[i][j] = wv;
        psum += wv;
      }
      psum += __shfl_xor(psum, 1);
      psum += __shfl_xor(psum, 2);
      psum += __shfl_xor(psum, 4);
      psum += __shfl_xor(psum, 8);
      wsum[i] += psum;
    }
    // stage W transposed+swizzled: Wt[s][t^swz]
    #pragma unroll
    for (int j = 0; j < 4; ++j) {
      int srow = tx * 4 + j;
      float4 wv4 = make_float4(w[0][j], w[1][j], w[2][j], w[3][j]);
      *(float4*)&Wt[srow * 68 + ((ty * 4) ^ SW(srow))] = wv4;
    }
    __syncthreads();
    // phase 2: acc[t][d] += sum_s Wt[s][t] * Vs[s][d]
    #pragma unroll 8
    for (int s = 0; s < 64; ++s) {
      float4 av = *(const float4*)&Wt[s * 68 + ((ty * 4) ^ SW(s))];
      float4 bv = *(const float4*)&Vs[s * 68 + tx * 4];
      float a0[4] = {av.x, av.y, av.z, av.w};
      float b0[4] = {bv.x, bv.y, bv.z, bv.w};
      #pragma unroll
      for (int i = 0; i < 4; ++i)
        #pragma unroll
        for (int j = 0; j < 4; ++j) acc[i][j] += a0[i] * b0[j];
    }
  }
  #pragma unroll
  for (int i = 0; i < 4; ++i) {
    int t = t0 + ty * 4 + i;
    if (t < SS) {
      float rn = 1.f / fmaxf(fabsf(wsum[i]), nfloor[i]);
      float4 o = make_float4(acc[i][0] * rn, acc[i][1] * rn, acc[i][2] * rn, acc[i][3] * rn);
      *(float4*)&hb[((size_t)b * SS + t) * II + h * 64 + tx * 4] = o;
    }
  }
}

// ---------------------------------------------------------------------------
// per-head LN + skip*xc + *silu(z)
// ---------------------------------------------------------------------------
__global__ __launch_bounds__(256) void mhln_kernel(
    const float* __restrict__ up, const float* __restrict__ xc,
    const float* __restrict__ mhg, const float* __restrict__ skip,
    float* __restrict__ hb)
{
  int row = blockIdx.x;
  int h = threadIdx.x >> 6, lane = threadIdx.x & 63;
  int i = h * DHH + lane;
  float hv = hb[(size_t)row * II + i];
  float s = hv, sq = hv * hv;
  #pragma unroll
  for (int d = 1; d < 64; d <<= 1) { s += __shfl_xor(s, d); sq += __shfl_xor(sq, d); }
  float mu = s * (1.f / 64.f);
  float var = sq * (1.f / 64.f) - mu * mu;
  float hn = (hv - mu) * rsqrtf(var + 1e-5f) * mhg[i];
  float z = up[(size_t)row * 512 + 256 + i];
  float sil = z / (1.f + __expf(-z));
  hb[(size_t)row * II + i] = (hn + skip[i] * xc[(size_t)row * II + i]) * sil;
}

// ---------------------------------------------------------------------------
// final: out[b,p,c] = LN(x)@Wp2^T + bp2 (float4 inner loop)
// ---------------------------------------------------------------------------
__global__ __launch_bounds__(256) void final_kernel(
    const float* __restrict__ y, const float* __restrict__ Wp2,
    const float* __restrict__ bp2, float* __restrict__ out)
{
  __shared__ float yl[32 * 132];
  __shared__ float ol[96 * 32];
  int tid = threadIdx.x;
  int blk = blockIdx.x;
  int b = blk / 27, ct = blk % 27;
  int c0 = ct * 32;
  int nc = CC - c0; if (nc > 32) nc = 32;
  for (int j = 0; j < 16; ++j) {
    int idx = tid + j * 256;
    int cl = idx >> 7, d2 = idx & 127;
    yl[cl * 132 + d2] = (cl < nc) ? y[((size_t)b * CC + c0 + cl) * DD + d2] : 0.f;
  }
  __syncthreads();
  for (int j = 0; j < 12; ++j) {
    int o = tid + j * 256;
    int p = o >> 5, cl = o & 31;
    const float* wr = Wp2 + p * 128;
    float acc = bp2[p];
    #pragma unroll 8
    for (int d0 = 0; d0 < 128; d0 += 4) {
      float4 yv = *(const float4*)&yl[cl * 132 + d0];
      float4 wv = *(const float4*)&wr[d0];
      acc += yv.x * wv.x + yv.y * wv.y + yv.z * wv.z + yv.w * wv.w;
    }
    ol[p * 32 + cl] = acc;
  }
  __syncthreads();
  for (int j = 0; j < 12; ++j) {
    int o = tid + j * 256;
    int p = o >> 5, cl = o & 31;
    if (cl < nc) out[(size_t)b * PP * CC + (size_t)p * CC + c0 + cl] = ol[p * 32 + cl];
  }
}

// ---------------------------------------------------------------------------
extern "C" void kernel_launch(void* const* d_in, const int* in_sizes, int n_in,
                              void* d_out, int out_size, void* d_ws, size_t ws_size,
                              hipStream_t stream) {
  const float* xe   = (const float*)d_in[0];
  const float* Ws   = (const float*)d_in[4];
  const float* bs   = (const float*)d_in[5];
  const float* Wt_  = (const float*)d_in[6];
  const float* bt   = (const float*)d_in[7];
  const float* Wp1  = (const float*)d_in[8];
  const float* bp1  = (const float*)d_in[9];
  const float* Wp2  = (const float*)d_in[10];
  const float* bp2  = (const float*)d_in[11];
  const float* lng  = (const float*)d_in[12];
  const float* Wup  = (const float*)d_in[13];
  const float* bup  = (const float*)d_in[14];
  const float* Wcv  = (const float*)d_in[15];
  const float* bcv  = (const float*)d_in[16];
  const float* Wq   = (const float*)d_in[17];
  const float* Wk   = (const float*)d_in[18];
  const float* Wv   = (const float*)d_in[19];
  const float* Wi   = (const float*)d_in[20];
  const float* bi   = (const float*)d_in[21];
  const float* Wf   = (const float*)d_in[22];
  const float* bf_  = (const float*)d_in[23];
  const float* mhg  = (const float*)d_in[24];
  const float* skp  = (const float*)d_in[25];
  const float* Wdn  = (const float*)d_in[26];
  const float* bdn  = (const float*)d_in[27];
  const float* pg   = (const float*)d_in[28];
  float* out = (float*)d_out;

  float* w   = (float*)d_ws;
  float* x   = w;                       // [6896,128]
  float* y   = x   + 882688;            // [6896,128]
  float* up  = y   + 882688;            // [6896,512]
  float* xc  = up  + 3530752;           // [6896,256]
  float* q   = xc  + 1765376;           // [6896,256]
  float* k   = q   + 1765376;           // [6896,256]
  float* v   = k   + 1765376;           // [6896,256]
  float* ig  = v   + 1765376;           // [8,4,862]
  float* fg  = ig  + 27584;
  float* cum = fg  + 27584;
  float* aab = cum + 27584;
  float* MMb = aab + 27584;
  float* hb  = MMb + 27584;             // [6896,256]

  head_kernel<<<864, 256, 0, stream>>>(xe, Ws, bs, Wt_, bt, Wp1, bp1, x);

  for (int blk = 0; blk < 2; ++blk) {
    ln_kernel<<<1724, 256, 0, stream>>>(x, lng + blk * 128, y, BC);
    gemm_f32<false, true><<<dim3(8, 108), 256, 0, stream>>>(
        y, 128, Wup + blk * 128 * 512, 512, up, 512, bup + blk * 512, BC, 512, 128);
    conv_silu_kernel<<<6896, 256, 0, stream>>>(up, Wcv + blk * 4 * 256, bcv + blk * 256, xc);
    gemm_f32<false, false><<<dim3(4, 108), 256, 0, stream>>>(
        xc, 256, Wq + blk * 65536, 256, q, 256, nullptr, BC, 256, 256);
    gemm_f32<false, false><<<dim3(4, 108), 256, 0, stream>>>(
        xc, 256, Wk + blk * 65536, 256, k, 256, nullptr, BC, 256, 256);
    gemm_f32<false, false><<<dim3(4, 108), 256, 0, stream>>>(
        up, 512, Wv + blk * 65536, 256, v, 256, nullptr, BC, 256, 256);
    gates_kernel<<<1724, 256, 0, stream>>>(q, k, v, Wi + blk * 3072, bi + blk * 4,
                                           Wf + blk * 3072, bf_ + blk * 4, ig, fg);
    scan_kernel<<<32, 64, 0, stream>>>(fg, ig, cum, aab, MMb);
    attn_kernel<<<dim3(14, 4, 8), 256, 0, stream>>>(q, k, v, cum, aab, MMb, hb);
    mhln_kernel<<<6896, 256, 0, stream>>>(up, xc, mhg + blk * 256, skp + blk * 256, hb);
    gemm_f32<true, true><<<dim3(2, 108), 256, 0, stream>>>(
        hb, 256, Wdn + blk * 256 * 128, 128, x, 128, bdn + blk * 128, BC, 128, 256);
  }

  ln_kernel<<<1724, 256, 0, stream>>>(x, pg, y, BC);
  final_kernel<<<216, 256, 0, stream>>>(y, Wp2, bp2, out);
}

// Round 5
// 454.625 us; speedup vs baseline: 7.1757x; 1.6404x over previous
//
#include <hip/hip_runtime.h>
#include <math.h>

#define BB 8
#define LL 512
#define CC 862
#define PP 96
#define DD 128
#define II 256
#define NHH 4
#define DHH 64
#define SS 862
#define BC (BB*CC)

typedef unsigned short u16;
using bf16x8 = __attribute__((ext_vector_type(8))) short;
using f32x4  = __attribute__((ext_vector_type(4))) float;

__device__ __forceinline__ u16 f2b(float x) {
  union { float f; unsigned u; } v; v.f = x;
  unsigned r = v.u + 0x7FFF + ((v.u >> 16) & 1);
  return (u16)(r >> 16);
}

// ---------------------------------------------------------------------------
// fused transpose-convert of weights to bf16 [N][K] layouts (10 tiles)
// ---------------------------------------------------------------------------
__global__ __launch_bounds__(256) void tc_kernel(
    const float* __restrict__ Wup, const float* __restrict__ Wq,
    const float* __restrict__ Wk, const float* __restrict__ Wv,
    const float* __restrict__ Wdn,
    u16* __restrict__ WupT, u16* __restrict__ WqkT,
    u16* __restrict__ WvT, u16* __restrict__ WdnT)
{
  const float* src; u16* dst; int R, Cn;
  switch (blockIdx.y) {
    case 0: src = Wup;          dst = WupT;            R = 128; Cn = 512; break;
    case 1: src = Wup + 65536;  dst = WupT + 65536;    R = 128; Cn = 512; break;
    case 2: src = Wq;           dst = WqkT;            R = 256; Cn = 256; break;
    case 3: src = Wk;           dst = WqkT + 65536;    R = 256; Cn = 256; break;
    case 4: src = Wq + 65536;   dst = WqkT + 131072;   R = 256; Cn = 256; break;
    case 5: src = Wk + 65536;   dst = WqkT + 196608;   R = 256; Cn = 256; break;
    case 6: src = Wv;           dst = WvT;             R = 256; Cn = 256; break;
    case 7: src = Wv + 65536;   dst = WvT + 65536;     R = 256; Cn = 256; break;
    case 8: src = Wdn;          dst = WdnT;            R = 256; Cn = 128; break;
    default: src = Wdn + 32768; dst = WdnT + 32768;    R = 256; Cn = 128; break;
  }
  int tpr = Cn >> 5;
  int tx = blockIdx.x % tpr, ty_ = blockIdx.x / tpr;
  if (ty_ >= (R >> 5)) return;
  __shared__ float t[32][33];
  int tid = threadIdx.x;
  int r0 = ty_ * 32, c0 = tx * 32;
  int cr = tid >> 5, cc = tid & 31;
  #pragma unroll
  for (int rr = 0; rr < 4; ++rr)
    t[cr + rr * 8][cc] = src[(size_t)(r0 + cr + rr * 8) * Cn + c0 + cc];
  __syncthreads();
  #pragma unroll
  for (int rr = 0; rr < 4; ++rr)
    dst[(size_t)(c0 + cr + rr * 8) * R + r0 + cc] = f2b(t[cc][cr + rr * 8]);
}

// ---------------------------------------------------------------------------
// combined head weight: BTh[d][l'] ; l'<512: Wp1.Ws ; else Wp1.(Wt-Ws)
// ---------------------------------------------------------------------------
__global__ __launch_bounds__(256) void gcomb_kernel(
    const float* __restrict__ Ws, const float* __restrict__ Wt,
    const float* __restrict__ Wp1, u16* __restrict__ BTh)
{
  int d = blockIdx.x;
  int lp = blockIdx.y * 256 + threadIdx.x;
  const float* wp = Wp1 + d * 96;
  float acc = 0.f;
  if (lp < 512) {
    for (int p = 0; p < 96; ++p) acc += Ws[p * 512 + lp] * wp[p];
  } else {
    int l = lp - 512;
    for (int p = 0; p < 96; ++p) acc += (Wt[p * 512 + l] - Ws[p * 512 + l]) * wp[p];
  }
  BTh[(size_t)d * 1024 + lp] = f2b(acc);
}

__global__ __launch_bounds__(128) void hbias_kernel(
    const float* __restrict__ bs, const float* __restrict__ bt,
    const float* __restrict__ Wp1, const float* __restrict__ bp1,
    float* __restrict__ hbias)
{
  int d = threadIdx.x;
  float acc = bp1[d];
  for (int p = 0; p < 96; ++p) acc += (bs[p] + bt[p]) * Wp1[d * 96 + p];
  hbias[d] = acc;
}

// ---------------------------------------------------------------------------
// transpose + moving-average -> bf16 A_head [6896][1024]  (xe_t | mm_t)
// ---------------------------------------------------------------------------
__global__ __launch_bounds__(256) void ta_kernel(
    const float* __restrict__ xe, u16* __restrict__ Ah)
{
  __shared__ float xel[8][548];
  __shared__ float mml[8][516];
  int tid = threadIdx.x;
  int b = blockIdx.x / 108, ct = blockIdx.x % 108;
  int c0 = ct * 8;
  for (int j = 0; j < 17; ++j) {
    int idx = tid + j * 256;
    if (idx < 4288) {
      int li = idx >> 3, cl = idx & 7;
      int l = li - 12; l = l < 0 ? 0 : (l > 511 ? 511 : l);
      int c = c0 + cl; if (c > 861) c = 861;
      xel[cl][li] = xe[((size_t)b * LL + l) * CC + c];
    }
  }
  __syncthreads();
  {
    int cl = tid & 7;
    int l0 = (tid >> 3) * 16;
    float win = 0.f;
    #pragma unroll 5
    for (int o = 0; o < 25; ++o) win += xel[cl][l0 + o];
    mml[cl][l0] = win * (1.f / 25.f);
    for (int i = 1; i < 16; ++i) {
      win += xel[cl][l0 + 24 + i] - xel[cl][l0 + i - 1];
      mml[cl][l0 + i] = win * (1.f / 25.f);
    }
  }
  __syncthreads();
  for (int j = 0; j < 32; ++j) {
    int idx = tid + j * 256;
    int cl = idx >> 10, col = idx & 1023;
    int c = c0 + cl;
    if (c < CC) {
      float vsrc = (col < 512) ? xel[cl][12 + col] : mml[cl][col - 512];
      Ah[((size_t)b * CC + c) * 1024 + col] = f2b(vsrc);
    }
  }
}

// ---------------------------------------------------------------------------
// bf16 MFMA GEMM: C[M,N] = A[M,K](bf16) @ BT[N,K](bf16)^T  (+bias)(+=)
// 64x64 tile, 4 waves (2x2), each wave 32x32 via 2x2 16x16x32 MFMA frags.
// ---------------------------------------------------------------------------
template<bool ACC, bool BIAS>
__global__ __launch_bounds__(256) void gemm_bf16(
    const u16* __restrict__ A, int lda,
    const u16* __restrict__ BT, int ldbt,
    float* __restrict__ C, int ldc,
    const float* __restrict__ bias,
    int M, int N, int K)
{
  __shared__ u16 As[64][40];
  __shared__ u16 Bs[64][40];
  int tid = threadIdx.x;
  int m0 = blockIdx.y * 64, n0 = blockIdx.x * 64;
  int wv = tid >> 6, lane = tid & 63;
  int wr = wv >> 1, wc = wv & 1;
  int lrow = lane & 15, lk = lane >> 4;
  f32x4 acc[2][2] = {};
  int arow = tid >> 2, aseg = tid & 3;
  for (int k0 = 0; k0 < K; k0 += 32) {
    int gm = m0 + arow; if (gm > M - 1) gm = M - 1;
    *(uint4*)&As[arow][aseg * 8] = *(const uint4*)&A[(size_t)gm * lda + k0 + aseg * 8];
    int gn = n0 + arow;
    *(uint4*)&Bs[arow][aseg * 8] = *(const uint4*)&BT[(size_t)gn * ldbt + k0 + aseg * 8];
    __syncthreads();
    bf16x8 af[2], bfr[2];
    #pragma unroll
    for (int fm = 0; fm < 2; ++fm)
      af[fm] = *(const bf16x8*)&As[wr * 32 + fm * 16 + lrow][lk * 8];
    #pragma unroll
    for (int fn = 0; fn < 2; ++fn)
      bfr[fn] = *(const bf16x8*)&Bs[wc * 32 + fn * 16 + lrow][lk * 8];
    #pragma unroll
    for (int fm = 0; fm < 2; ++fm)
      #pragma unroll
      for (int fn = 0; fn < 2; ++fn)
        acc[fm][fn] = __builtin_amdgcn_mfma_f32_16x16x32_bf16(af[fm], bfr[fn], acc[fm][fn], 0, 0, 0);
    __syncthreads();
  }
  #pragma unroll
  for (int fm = 0; fm < 2; ++fm) {
    #pragma unroll
    for (int fn = 0; fn < 2; ++fn) {
      int col = n0 + wc * 32 + fn * 16 + lrow;
      #pragma unroll
      for (int r = 0; r < 4; ++r) {
        int row = m0 + wr * 32 + fm * 16 + lk * 4 + r;
        if (row < M) {
          float vv = acc[fm][fn][r];
          if (BIAS) vv += bias[col];
          float* cp = &C[(size_t)row * ldc + col];
          if (ACC) vv += *cp;
          *cp = vv;
        }
      }
    }
  }
}

// ---------------------------------------------------------------------------
// Row LayerNorm (D=128): writes fp32 + bf16
// ---------------------------------------------------------------------------
__global__ __launch_bounds__(256) void ln_kernel(
    const float* __restrict__ x, const float* __restrict__ g,
    float* __restrict__ y, u16* __restrict__ y_bf, int nrows)
{
  int row = blockIdx.x * 4 + (threadIdx.x >> 6);
  int lane = threadIdx.x & 63;
  if (row >= nrows) return;
  const float* xr = x + (size_t)row * DD;
  float a = xr[lane], b2 = xr[lane + 64];
  float s = a + b2, sq = a * a + b2 * b2;
  #pragma unroll
  for (int d = 1; d < 64; d <<= 1) { s += __shfl_xor(s, d); sq += __shfl_xor(sq, d); }
  float mean = s * (1.f / 128.f);
  float var = sq * (1.f / 128.f) - mean * mean;
  float r = rsqrtf(var + 1e-5f);
  float v0 = (a - mean) * r * g[lane];
  float v1 = (b2 - mean) * r * g[64 + lane];
  y[(size_t)row * DD + lane] = v0;
  y[(size_t)row * DD + 64 + lane] = v1;
  y_bf[(size_t)row * DD + lane] = f2b(v0);
  y_bf[(size_t)row * DD + 64 + lane] = f2b(v1);
}

// ---------------------------------------------------------------------------
// causal depthwise conv (k=4) + bias + SiLU; emits xc fp32, xc bf16, xin bf16
// ---------------------------------------------------------------------------
__global__ __launch_bounds__(256) void conv_silu_kernel(
    const float* __restrict__ up, const float* __restrict__ Wc,
    const float* __restrict__ bc, float* __restrict__ xc,
    u16* __restrict__ xc_bf, u16* __restrict__ xin_bf)
{
  int row = blockIdx.x;
  int i = threadIdx.x;
  int b = row / SS, s = row - b * SS;
  float acc = bc[i];
  float xin = 0.f;
  #pragma unroll
  for (int w2 = 0; w2 < 4; ++w2) {
    int sp = s - 3 + w2;
    if (sp >= 0) {
      float uv = up[((size_t)b * SS + sp) * 512 + i];
      acc += uv * Wc[w2 * 256 + i];
      if (w2 == 3) xin = uv;
    }
  }
  float sg = 1.f / (1.f + __expf(-acc));
  float val = acc * sg;
  xc[(size_t)row * II + i] = val;
  xc_bf[(size_t)row * II + i] = f2b(val);
  xin_bf[(size_t)row * II + i] = f2b(xin);
}

// ---------------------------------------------------------------------------
// gate preacts (qk fused buffer stride 512, v stride 256)
// ---------------------------------------------------------------------------
__global__ __launch_bounds__(256) void gates_kernel(
    const float* __restrict__ qk, const float* __restrict__ v,
    const float* __restrict__ Wi, const float* __restrict__ bi,
    const float* __restrict__ Wf, const float* __restrict__ bfp,
    float* __restrict__ ig, float* __restrict__ fg)
{
  int row = blockIdx.x * 4 + (threadIdx.x >> 6);
  int lane = threadIdx.x & 63;
  float acc[8] = {};
  for (int j = lane; j < 768; j += 64) {
    float gv = (j < 512) ? qk[(size_t)row * 512 + j] : v[(size_t)row * II + j - 512];
    float4 wi4 = *(const float4*)&Wi[j * 4];
    float4 wf4 = *(const float4*)&Wf[j * 4];
    acc[0] += gv * wi4.x; acc[1] += gv * wi4.y; acc[2] += gv * wi4.z; acc[3] += gv * wi4.w;
    acc[4] += gv * wf4.x; acc[5] += gv * wf4.y; acc[6] += gv * wf4.z; acc[7] += gv * wf4.w;
  }
  #pragma unroll
  for (int o = 0; o < 8; ++o)
    #pragma unroll
    for (int d2 = 1; d2 < 64; d2 <<= 1) acc[o] += __shfl_xor(acc[o], d2);
  int b = row / SS, s = row - b * SS;
  if (lane < 4) {
    ig[((size_t)b * NHH + lane) * SS + s] = acc[lane] + bi[lane];
  } else if (lane < 8) {
    int o = lane - 4;
    fg[((size_t)b * NHH + o) * SS + s] = acc[4 + o] + bfp[o];
  }
}

// ---------------------------------------------------------------------------
// per-(b,h) scan
// ---------------------------------------------------------------------------
__device__ __forceinline__ float logsig(float x) {
  return fminf(x, 0.f) - log1pf(__expf(-fabsf(x)));
}

__global__ __launch_bounds__(64) void scan_kernel(
    const float* __restrict__ fg, const float* __restrict__ ig,
    float* __restrict__ cumf, float* __restrict__ aa, float* __restrict__ MMb)
{
  int bh = blockIdx.x;
  int lane = threadIdx.x;
  const float* f = fg + (size_t)bh * SS;
  const float* g = ig + (size_t)bh * SS;
  int s0 = lane * 14, s1 = s0 + 14; if (s1 > SS) s1 = SS;
  float loc = 0.f;
  for (int s = s0; s < s1; ++s) loc += logsig(f[s]);
  float v = loc;
  #pragma unroll
  for (int d = 1; d < 64; d <<= 1) { float o = __shfl_up(v, d); if (lane >= d) v += o; }
  float run = v - loc;
  float lmax = -1e30f;
  for (int s = s0; s < s1; ++s) {
    run += logsig(f[s]);
    cumf[(size_t)bh * SS + s] = run;
    float a = g[s] - run;
    aa[(size_t)bh * SS + s] = a;
    lmax = fmaxf(lmax, a);
  }
  float mv = lmax;
  #pragma unroll
  for (int d = 1; d < 64; d <<= 1) { float o = __shfl_up(mv, d); if (lane >= d) mv = fmaxf(mv, o); }
  float em = __shfl_up(mv, 1);
  if (lane == 0) em = -1e30f;
  float runm = em;
  for (int s = s0; s < s1; ++s) {
    runm = fmaxf(runm, aa[(size_t)bh * SS + s]);
    MMb[(size_t)bh * SS + s] = runm;
  }
}

// ---------------------------------------------------------------------------
// masked decay attention — dual-GEMM fp32 (q,k in fused qk buffer)
// ---------------------------------------------------------------------------
#define SW(r) ((((r) >> 2) & 7) << 2)

__global__ __launch_bounds__(256) void attn_kernel(
    const float* __restrict__ qk, const float* __restrict__ vb,
    const float* __restrict__ cumf, const float* __restrict__ aab, const float* __restrict__ MMb,
    float* __restrict__ hb)
{
  __shared__ float QT[64 * 68];
  __shared__ float KT[64 * 68];
  __shared__ float Vs[64 * 68];
  __shared__ float Wt[64 * 68];
  __shared__ float a_lds[64];
  int tid = threadIdx.x;
  int tx = tid & 15, ty = tid >> 4;
  int lane = tid & 63;
  int tb = 13 - blockIdx.x;
  int h = blockIdx.y, b = blockIdx.z;
  int t0 = tb * 64;
  const float* aabh  = aab  + ((size_t)b * NHH + h) * SS;
  const float* Mbh   = MMb  + ((size_t)b * NHH + h) * SS;
  const float* cumbh = cumf + ((size_t)b * NHH + h) * SS;

  for (int it = 0; it < 4; ++it) {
    int idx = tid + it * 256;
    int s = idx >> 4, d0 = (idx & 15) * 4;
    int t = t0 + s;
    float4 qv = make_float4(0.f, 0.f, 0.f, 0.f);
    if (t < SS) qv = *(const float4*)&qk[((size_t)b * SS + t) * 512 + h * 64 + d0];
    int sw = s ^ SW(d0);
    QT[(d0 + 0) * 68 + sw] = qv.x * 0.125f;
    QT[(d0 + 1) * 68 + sw] = qv.y * 0.125f;
    QT[(d0 + 2) * 68 + sw] = qv.z * 0.125f;
    QT[(d0 + 3) * 68 + sw] = qv.w * 0.125f;
  }
  float Mt[4], nfloor[4];
  #pragma unroll
  for (int i = 0; i < 4; ++i) {
    int t = t0 + ty * 4 + i; int tc = t < SS ? t : SS - 1;
    Mt[i] = Mbh[tc];
    nfloor[i] = __expf(-(cumbh[tc] + Mt[i]));
  }
  float acc[4][4] = {};
  float wsum[4] = {0.f, 0.f, 0.f, 0.f};
  int tlast = t0 + 63; if (tlast > SS - 1) tlast = SS - 1;
  int ntiles = tlast / 64 + 1;

  for (int st = 0; st < ntiles; ++st) {
    int s0 = st * 64;
    __syncthreads();
    for (int it = 0; it < 4; ++it) {
      int idx = tid + it * 256;
      int s = idx >> 4, d0 = (idx & 15) * 4;
      int sg = s0 + s;
      float4 kv = make_float4(0.f, 0.f, 0.f, 0.f);
      float4 vv = make_float4(0.f, 0.f, 0.f, 0.f);
      if (sg < SS) {
        kv = *(const float4*)&qk[((size_t)b * SS + sg) * 512 + 256 + h * 64 + d0];
        vv = *(const float4*)&vb[((size_t)b * SS + sg) * II + h * 64 + d0];
      }
      int sw = s ^ SW(d0);
      KT[(d0 + 0) * 68 + sw] = kv.x;
      KT[(d0 + 1) * 68 + sw] = kv.y;
      KT[(d0 + 2) * 68 + sw] = kv.z;
      KT[(d0 + 3) * 68 + sw] = kv.w;
      *(float4*)&Vs[s * 68 + d0] = vv;
    }
    if (tid < 64) {
      int sg = s0 + tid;
      a_lds[tid] = (sg < SS) ? aabh[sg] : -1e30f;
    }
    __syncthreads();
    float am = a_lds[lane];
    #pragma unroll
    for (int dd = 1; dd < 64; dd <<= 1) am = fmaxf(am, __shfl_xor(am, dd));
    float p[4][4] = {};
    #pragma unroll 8
    for (int d = 0; d < 64; ++d) {
      float4 av = *(const float4*)&QT[d * 68 + ((ty * 4) ^ SW(d))];
      float4 bv = *(const float4*)&KT[d * 68 + ((tx * 4) ^ SW(d))];
      float a0[4] = {av.x, av.y, av.z, av.w};
      float b0[4] = {bv.x, bv.y, bv.z, bv.w};
      #pragma unroll
      for (int i = 0; i < 4; ++i)
        #pragma unroll
        for (int j = 0; j < 4; ++j) p[i][j] += a0[i] * b0[j];
    }
    float ee[4], ft[4];
    #pragma unroll
    for (int j = 0; j < 4; ++j) ee[j] = __expf(a_lds[tx * 4 + j] - am);
    #pragma unroll
    for (int i = 0; i < 4; ++i) ft[i] = __expf(fminf(am - Mt[i], 80.f));
    float w[4][4];
    #pragma unroll
    for (int i = 0; i < 4; ++i) {
      int t = t0 + ty * 4 + i;
      float psum = 0.f;
      #pragma unroll
      for (int j = 0; j < 4; ++j) {
        int s = s0 + tx * 4 + j;
        float wv = (s <= t) ? p[i][j] * ee[j] * ft[i] : 0.f;
        w[i][j] = wv;
        psum += wv;
      }
      psum += __shfl_xor(psum, 1);
      psum += __shfl_xor(psum, 2);
      psum += __shfl_xor(psum, 4);
      psum += __shfl_xor(psum, 8);
      wsum[i] += psum;
    }
    #pragma unroll
    for (int j = 0; j < 4; ++j) {
      int srow = tx * 4 + j;
      float4 wv4 = make_float4(w[0][j], w[1][j], w[2][j], w[3][j]);
      *(float4*)&Wt[srow * 68 + ((ty * 4) ^ SW(srow))] = wv4;
    }
    __syncthreads();
    #pragma unroll 8
    for (int s = 0; s < 64; ++s) {
      float4 av = *(const float4*)&Wt[s * 68 + ((ty * 4) ^ SW(s))];
      float4 bv = *(const float4*)&Vs[s * 68 + tx * 4];
      float a0[4] = {av.x, av.y, av.z, av.w};
      float b0[4] = {bv.x, bv.y, bv.z, bv.w};
      #pragma unroll
      for (int i = 0; i < 4; ++i)
        #pragma unroll
        for (int j = 0; j < 4; ++j) acc[i][j] += a0[i] * b0[j];
    }
  }
  #pragma unroll
  for (int i = 0; i < 4; ++i) {
    int t = t0 + ty * 4 + i;
    if (t < SS) {
      float rn = 1.f / fmaxf(fabsf(wsum[i]), nfloor[i]);
      float4 o = make_float4(acc[i][0] * rn, acc[i][1] * rn, acc[i][2] * rn, acc[i][3] * rn);
      *(float4*)&hb[((size_t)b * SS + t) * II + h * 64 + tx * 4] = o;
    }
  }
}

// ---------------------------------------------------------------------------
// per-head LN + skip*xc + *silu(z)  -> bf16
// ---------------------------------------------------------------------------
__global__ __launch_bounds__(256) void mhln_kernel(
    const float* __restrict__ up, const float* __restrict__ xc,
    const float* __restrict__ mhg, const float* __restrict__ skip,
    const float* __restrict__ hb, u16* __restrict__ hb_bf)
{
  int row = blockIdx.x;
  int h = threadIdx.x >> 6, lane = threadIdx.x & 63;
  int i = h * DHH + lane;
  float hv = hb[(size_t)row * II + i];
  float s = hv, sq = hv * hv;
  #pragma unroll
  for (int d = 1; d < 64; d <<= 1) { s += __shfl_xor(s, d); sq += __shfl_xor(sq, d); }
  float mu = s * (1.f / 64.f);
  float var = sq * (1.f / 64.f) - mu * mu;
  float hn = (hv - mu) * rsqrtf(var + 1e-5f) * mhg[i];
  float z = up[(size_t)row * 512 + 256 + i];
  float sil = z / (1.f + __expf(-z));
  hb_bf[(size_t)row * II + i] = f2b((hn + skip[i] * xc[(size_t)row * II + i]) * sil);
}

// ---------------------------------------------------------------------------
// final: out[b,p,c] = LN(x)@Wp2^T + bp2 (fp32)
// ---------------------------------------------------------------------------
__global__ __launch_bounds__(256) void final_kernel(
    const float* __restrict__ y, const float* __restrict__ Wp2,
    const float* __restrict__ bp2, float* __restrict__ out)
{
  __shared__ float yl[32 * 132];
  __shared__ float ol[96 * 32];
  int tid = threadIdx.x;
  int blk = blockIdx.x;
  int b = blk / 27, ct = blk % 27;
  int c0 = ct * 32;
  int nc = CC - c0; if (nc > 32) nc = 32;
  for (int j = 0; j < 16; ++j) {
    int idx = tid + j * 256;
    int cl = idx >> 7, d2 = idx & 127;
    yl[cl * 132 + d2] = (cl < nc) ? y[((size_t)b * CC + c0 + cl) * DD + d2] : 0.f;
  }
  __syncthreads();
  for (int j = 0; j < 12; ++j) {
    int o = tid + j * 256;
    int p = o >> 5, cl = o & 31;
    const float* wr = Wp2 + p * 128;
    float acc = bp2[p];
    #pragma unroll 8
    for (int d0 = 0; d0 < 128; d0 += 4) {
      float4 yv = *(const float4*)&yl[cl * 132 + d0];
      float4 wv = *(const float4*)&wr[d0];
      acc += yv.x * wv.x + yv.y * wv.y + yv.z * wv.z + yv.w * wv.w;
    }
    ol[p * 32 + cl] = acc;
  }
  __syncthreads();
  for (int j = 0; j < 12; ++j) {
    int o = tid + j * 256;
    int p = o >> 5, cl = o & 31;
    if (cl < nc) out[(size_t)b * PP * CC + (size_t)p * CC + c0 + cl] = ol[p * 32 + cl];
  }
}

// ---------------------------------------------------------------------------
extern "C" void kernel_launch(void* const* d_in, const int* in_sizes, int n_in,
                              void* d_out, int out_size, void* d_ws, size_t ws_size,
                              hipStream_t stream) {
  const float* xe   = (const float*)d_in[0];
  const float* Ws   = (const float*)d_in[4];
  const float* bs   = (const float*)d_in[5];
  const float* Wt_  = (const float*)d_in[6];
  const float* bt   = (const float*)d_in[7];
  const float* Wp1  = (const float*)d_in[8];
  const float* bp1  = (const float*)d_in[9];
  const float* Wp2  = (const float*)d_in[10];
  const float* bp2  = (const float*)d_in[11];
  const float* lng  = (const float*)d_in[12];
  const float* Wup  = (const float*)d_in[13];
  const float* bup  = (const float*)d_in[14];
  const float* Wcv  = (const float*)d_in[15];
  const float* bcv  = (const float*)d_in[16];
  const float* Wq   = (const float*)d_in[17];
  const float* Wk   = (const float*)d_in[18];
  const float* Wv   = (const float*)d_in[19];
  const float* Wi   = (const float*)d_in[20];
  const float* bi   = (const float*)d_in[21];
  const float* Wf   = (const float*)d_in[22];
  const float* bf_  = (const float*)d_in[23];
  const float* mhg  = (const float*)d_in[24];
  const float* skp  = (const float*)d_in[25];
  const float* Wdn  = (const float*)d_in[26];
  const float* bdn  = (const float*)d_in[27];
  const float* pg   = (const float*)d_in[28];
  float* out = (float*)d_out;

  float* w   = (float*)d_ws;
  float* x   = w;                       // [6896,128]
  float* y   = x   + 882688;
  float* up  = y   + 882688;            // [6896,512]  (aliased by A_head bf16)
  float* xc  = up  + 3530752;           // [6896,256]
  float* qk  = xc  + 1765376;           // [6896,512]
  float* v   = qk  + 3530752;           // [6896,256]
  float* hb  = v   + 1765376;           // [6896,256]
  float* ig  = hb  + 1765376;
  float* fg  = ig  + 27584;
  float* cum = fg  + 27584;
  float* aab = cum + 27584;
  float* MMb = aab + 27584;
  u16* ub    = (u16*)(MMb + 27584);
  u16* y_bf  = ub;            ub += 6896 * 128;
  u16* xc_bf = ub;            ub += 6896 * 256;
  u16* xin_bf = ub;           ub += 6896 * 256;
  u16* hb_bf = ub;            ub += 6896 * 256;
  u16* BTh   = ub;            ub += 131072;
  u16* WupT  = ub;            ub += 131072;   // 2 blocks x [512][128]
  u16* WqkT  = ub;            ub += 262144;
  u16* WvT   = ub;            ub += 131072;
  u16* WdnT  = ub;            ub += 65536;
  float* hbias = (float*)ub;
  u16* Ah = (u16*)up;                   // A_head aliases up

  // weight prep
  tc_kernel<<<dim3(64, 10), 256, 0, stream>>>(Wup, Wq, Wk, Wv, Wdn, WupT, WqkT, WvT, WdnT);
  gcomb_kernel<<<dim3(128, 4), 256, 0, stream>>>(Ws, Wt_, Wp1, BTh);
  hbias_kernel<<<1, 128, 0, stream>>>(bs, bt, Wp1, bp1, hbias);

  // head
  ta_kernel<<<864, 256, 0, stream>>>(xe, Ah);
  gemm_bf16<false, true><<<dim3(2, 108), 256, 0, stream>>>(
      Ah, 1024, BTh, 1024, x, 128, hbias, BC, 128, 1024);

  for (int blk = 0; blk < 2; ++blk) {
    ln_kernel<<<1724, 256, 0, stream>>>(x, lng + blk * 128, y, y_bf, BC);
    gemm_bf16<false, true><<<dim3(8, 108), 256, 0, stream>>>(
        y_bf, 128, WupT + blk * 65536, 128, up, 512, bup + blk * 512, BC, 512, 128);
    conv_silu_kernel<<<6896, 256, 0, stream>>>(up, Wcv + blk * 1024, bcv + blk * 256,
                                               xc, xc_bf, xin_bf);
    gemm_bf16<false, false><<<dim3(8, 108), 256, 0, stream>>>(
        xc_bf, 256, WqkT + blk * 131072, 256, qk, 512, nullptr, BC, 512, 256);
    gemm_bf16<false, false><<<dim3(4, 108), 256, 0, stream>>>(
        xin_bf, 256, WvT + blk * 65536, 256, v, 256, nullptr, BC, 256, 256);
    gates_kernel<<<1724, 256, 0, stream>>>(qk, v, Wi + blk * 3072, bi + blk * 4,
                                           Wf + blk * 3072, bf_ + blk * 4, ig, fg);
    scan_kernel<<<32, 64, 0, stream>>>(fg, ig, cum, aab, MMb);
    attn_kernel<<<dim3(14, 4, 8), 256, 0, stream>>>(qk, v, cum, aab, MMb, hb);
    mhln_kernel<<<6896, 256, 0, stream>>>(up, xc, mhg + blk * 256, skp + blk * 256, hb, hb_bf);
    gemm_bf16<true, true><<<dim3(2, 108), 256, 0, stream>>>(
        hb_bf, 256, WdnT + blk * 32768, 256, x, 128, bdn + blk * 128, BC, 128, 256);
  }

  ln_kernel<<<1724, 256, 0, stream>>>(x, pg, y, y_bf, BC);
  final_kernel<<<216, 256, 0, stream>>>(y, Wp2, bp2, out);
}

// Round 6
// 338.320 us; speedup vs baseline: 9.6425x; 1.3438x over previous
//
#include <hip/hip_runtime.h>
#include <math.h>

#define BB 8
#define LL 512
#define CC 862
#define PP 96
#define DD 128
#define II 256
#define NHH 4
#define DHH 64
#define SS 862
#define BC (BB*CC)

typedef unsigned short u16;
using bf16x8 = __attribute__((ext_vector_type(8))) short;
using f32x4  = __attribute__((ext_vector_type(4))) float;

__device__ __forceinline__ u16 f2b(float x) {
  union { float f; unsigned u; } v; v.f = x;
  unsigned r = v.u + 0x7FFF + ((v.u >> 16) & 1);
  return (u16)(r >> 16);
}
__device__ __forceinline__ float b2f(u16 h) {
  union { unsigned u; float f; } v; v.u = ((unsigned)h) << 16;
  return v.f;
}

// ---------------------------------------------------------------------------
// fused transpose-convert of weights to bf16 [N][K] layouts (10 tiles)
// ---------------------------------------------------------------------------
__global__ __launch_bounds__(256) void tc_kernel(
    const float* __restrict__ Wup, const float* __restrict__ Wq,
    const float* __restrict__ Wk, const float* __restrict__ Wv,
    const float* __restrict__ Wdn,
    u16* __restrict__ WupT, u16* __restrict__ WqkT,
    u16* __restrict__ WvT, u16* __restrict__ WdnT)
{
  const float* src; u16* dst; int R, Cn;
  switch (blockIdx.y) {
    case 0: src = Wup;          dst = WupT;            R = 128; Cn = 512; break;
    case 1: src = Wup + 65536;  dst = WupT + 65536;    R = 128; Cn = 512; break;
    case 2: src = Wq;           dst = WqkT;            R = 256; Cn = 256; break;
    case 3: src = Wk;           dst = WqkT + 65536;    R = 256; Cn = 256; break;
    case 4: src = Wq + 65536;   dst = WqkT + 131072;   R = 256; Cn = 256; break;
    case 5: src = Wk + 65536;   dst = WqkT + 196608;   R = 256; Cn = 256; break;
    case 6: src = Wv;           dst = WvT;             R = 256; Cn = 256; break;
    case 7: src = Wv + 65536;   dst = WvT + 65536;     R = 256; Cn = 256; break;
    case 8: src = Wdn;          dst = WdnT;            R = 256; Cn = 128; break;
    default: src = Wdn + 32768; dst = WdnT + 32768;    R = 256; Cn = 128; break;
  }
  int tpr = Cn >> 5;
  int tx = blockIdx.x % tpr, ty_ = blockIdx.x / tpr;
  if (ty_ >= (R >> 5)) return;
  __shared__ float t[32][33];
  int tid = threadIdx.x;
  int r0 = ty_ * 32, c0 = tx * 32;
  int cr = tid >> 5, cc = tid & 31;
  #pragma unroll
  for (int rr = 0; rr < 4; ++rr)
    t[cr + rr * 8][cc] = src[(size_t)(r0 + cr + rr * 8) * Cn + c0 + cc];
  __syncthreads();
  #pragma unroll
  for (int rr = 0; rr < 4; ++rr)
    dst[(size_t)(c0 + cr + rr * 8) * R + r0 + cc] = f2b(t[cc][cr + rr * 8]);
}

// ---------------------------------------------------------------------------
// combined head weight: BTh[d][l'] ; l'<512: Wp1.Ws ; else Wp1.(Wt-Ws)
// ---------------------------------------------------------------------------
__global__ __launch_bounds__(256) void gcomb_kernel(
    const float* __restrict__ Ws, const float* __restrict__ Wt,
    const float* __restrict__ Wp1, u16* __restrict__ BTh)
{
  int d = blockIdx.x;
  int lp = blockIdx.y * 256 + threadIdx.x;
  const float* wp = Wp1 + d * 96;
  float acc = 0.f;
  if (lp < 512) {
    for (int p = 0; p < 96; ++p) acc += Ws[p * 512 + lp] * wp[p];
  } else {
    int l = lp - 512;
    for (int p = 0; p < 96; ++p) acc += (Wt[p * 512 + l] - Ws[p * 512 + l]) * wp[p];
  }
  BTh[(size_t)d * 1024 + lp] = f2b(acc);
}

__global__ __launch_bounds__(128) void hbias_kernel(
    const float* __restrict__ bs, const float* __restrict__ bt,
    const float* __restrict__ Wp1, const float* __restrict__ bp1,
    float* __restrict__ hbias)
{
  int d = threadIdx.x;
  float acc = bp1[d];
  for (int p = 0; p < 96; ++p) acc += (bs[p] + bt[p]) * Wp1[d * 96 + p];
  hbias[d] = acc;
}

// ---------------------------------------------------------------------------
// transpose + moving-average -> bf16 A_head [6896][1024]  (xe_t | mm_t)
// ---------------------------------------------------------------------------
__global__ __launch_bounds__(256) void ta_kernel(
    const float* __restrict__ xe, u16* __restrict__ Ah)
{
  __shared__ float xel[8][548];
  __shared__ float mml[8][516];
  int tid = threadIdx.x;
  int b = blockIdx.x / 108, ct = blockIdx.x % 108;
  int c0 = ct * 8;
  for (int j = 0; j < 17; ++j) {
    int idx = tid + j * 256;
    if (idx < 4288) {
      int li = idx >> 3, cl = idx & 7;
      int l = li - 12; l = l < 0 ? 0 : (l > 511 ? 511 : l);
      int c = c0 + cl; if (c > 861) c = 861;
      xel[cl][li] = xe[((size_t)b * LL + l) * CC + c];
    }
  }
  __syncthreads();
  {
    int cl = tid & 7;
    int l0 = (tid >> 3) * 16;
    float win = 0.f;
    #pragma unroll 5
    for (int o = 0; o < 25; ++o) win += xel[cl][l0 + o];
    mml[cl][l0] = win * (1.f / 25.f);
    for (int i = 1; i < 16; ++i) {
      win += xel[cl][l0 + 24 + i] - xel[cl][l0 + i - 1];
      mml[cl][l0 + i] = win * (1.f / 25.f);
    }
  }
  __syncthreads();
  for (int j = 0; j < 32; ++j) {
    int idx = tid + j * 256;
    int cl = idx >> 10, col = idx & 1023;
    int c = c0 + cl;
    if (c < CC) {
      float vsrc = (col < 512) ? xel[cl][12 + col] : mml[cl][col - 512];
      Ah[((size_t)b * CC + c) * 1024 + col] = f2b(vsrc);
    }
  }
}

// ---------------------------------------------------------------------------
// bf16 MFMA GEMM: C[M,N] = A[M,K](bf16) @ BT[N,K](bf16)^T  (+bias)(+=)
// ---------------------------------------------------------------------------
template<bool ACC, bool BIAS>
__global__ __launch_bounds__(256) void gemm_bf16(
    const u16* __restrict__ A, int lda,
    const u16* __restrict__ BT, int ldbt,
    float* __restrict__ C, int ldc,
    const float* __restrict__ bias,
    int M, int N, int K)
{
  __shared__ u16 As[64][40];
  __shared__ u16 Bs[64][40];
  int tid = threadIdx.x;
  int m0 = blockIdx.y * 64, n0 = blockIdx.x * 64;
  int wv = tid >> 6, lane = tid & 63;
  int wr = wv >> 1, wc = wv & 1;
  int lrow = lane & 15, lk = lane >> 4;
  f32x4 acc[2][2] = {};
  int arow = tid >> 2, aseg = tid & 3;
  for (int k0 = 0; k0 < K; k0 += 32) {
    int gm = m0 + arow; if (gm > M - 1) gm = M - 1;
    *(uint4*)&As[arow][aseg * 8] = *(const uint4*)&A[(size_t)gm * lda + k0 + aseg * 8];
    int gn = n0 + arow;
    *(uint4*)&Bs[arow][aseg * 8] = *(const uint4*)&BT[(size_t)gn * ldbt + k0 + aseg * 8];
    __syncthreads();
    bf16x8 af[2], bfr[2];
    #pragma unroll
    for (int fm = 0; fm < 2; ++fm)
      af[fm] = *(const bf16x8*)&As[wr * 32 + fm * 16 + lrow][lk * 8];
    #pragma unroll
    for (int fn = 0; fn < 2; ++fn)
      bfr[fn] = *(const bf16x8*)&Bs[wc * 32 + fn * 16 + lrow][lk * 8];
    #pragma unroll
    for (int fm = 0; fm < 2; ++fm)
      #pragma unroll
      for (int fn = 0; fn < 2; ++fn)
        acc[fm][fn] = __builtin_amdgcn_mfma_f32_16x16x32_bf16(af[fm], bfr[fn], acc[fm][fn], 0, 0, 0);
    __syncthreads();
  }
  #pragma unroll
  for (int fm = 0; fm < 2; ++fm) {
    #pragma unroll
    for (int fn = 0; fn < 2; ++fn) {
      int col = n0 + wc * 32 + fn * 16 + lrow;
      #pragma unroll
      for (int r = 0; r < 4; ++r) {
        int row = m0 + wr * 32 + fm * 16 + lk * 4 + r;
        if (row < M) {
          float vv = acc[fm][fn][r];
          if (BIAS) vv += bias[col];
          float* cp = &C[(size_t)row * ldc + col];
          if (ACC) vv += *cp;
          *cp = vv;
        }
      }
    }
  }
}

// ---------------------------------------------------------------------------
// Row LayerNorm (D=128): writes fp32 + bf16
// ---------------------------------------------------------------------------
__global__ __launch_bounds__(256) void ln_kernel(
    const float* __restrict__ x, const float* __restrict__ g,
    float* __restrict__ y, u16* __restrict__ y_bf, int nrows)
{
  int row = blockIdx.x * 4 + (threadIdx.x >> 6);
  int lane = threadIdx.x & 63;
  if (row >= nrows) return;
  const float* xr = x + (size_t)row * DD;
  float a = xr[lane], b2 = xr[lane + 64];
  float s = a + b2, sq = a * a + b2 * b2;
  #pragma unroll
  for (int d = 1; d < 64; d <<= 1) { s += __shfl_xor(s, d); sq += __shfl_xor(sq, d); }
  float mean = s * (1.f / 128.f);
  float var = sq * (1.f / 128.f) - mean * mean;
  float r = rsqrtf(var + 1e-5f);
  float v0 = (a - mean) * r * g[lane];
  float v1 = (b2 - mean) * r * g[64 + lane];
  y[(size_t)row * DD + lane] = v0;
  y[(size_t)row * DD + 64 + lane] = v1;
  y_bf[(size_t)row * DD + lane] = f2b(v0);
  y_bf[(size_t)row * DD + 64 + lane] = f2b(v1);
}

// ---------------------------------------------------------------------------
// causal depthwise conv (k=4) + bias + SiLU; emits xc fp32, xc bf16, xin bf16
// ---------------------------------------------------------------------------
__global__ __launch_bounds__(256) void conv_silu_kernel(
    const float* __restrict__ up, const float* __restrict__ Wc,
    const float* __restrict__ bc, float* __restrict__ xc,
    u16* __restrict__ xc_bf, u16* __restrict__ xin_bf)
{
  int row = blockIdx.x;
  int i = threadIdx.x;
  int b = row / SS, s = row - b * SS;
  float acc = bc[i];
  float xin = 0.f;
  #pragma unroll
  for (int w2 = 0; w2 < 4; ++w2) {
    int sp = s - 3 + w2;
    if (sp >= 0) {
      float uv = up[((size_t)b * SS + sp) * 512 + i];
      acc += uv * Wc[w2 * 256 + i];
      if (w2 == 3) xin = uv;
    }
  }
  float sg = 1.f / (1.f + __expf(-acc));
  float val = acc * sg;
  xc[(size_t)row * II + i] = val;
  xc_bf[(size_t)row * II + i] = f2b(val);
  xin_bf[(size_t)row * II + i] = f2b(xin);
}

// ---------------------------------------------------------------------------
// gate preacts (qk fused buffer stride 512, v stride 256)
// ---------------------------------------------------------------------------
__global__ __launch_bounds__(256) void gates_kernel(
    const float* __restrict__ qk, const float* __restrict__ v,
    const float* __restrict__ Wi, const float* __restrict__ bi,
    const float* __restrict__ Wf, const float* __restrict__ bfp,
    float* __restrict__ ig, float* __restrict__ fg)
{
  int row = blockIdx.x * 4 + (threadIdx.x >> 6);
  int lane = threadIdx.x & 63;
  float acc[8] = {};
  for (int j = lane; j < 768; j += 64) {
    float gv = (j < 512) ? qk[(size_t)row * 512 + j] : v[(size_t)row * II + j - 512];
    float4 wi4 = *(const float4*)&Wi[j * 4];
    float4 wf4 = *(const float4*)&Wf[j * 4];
    acc[0] += gv * wi4.x; acc[1] += gv * wi4.y; acc[2] += gv * wi4.z; acc[3] += gv * wi4.w;
    acc[4] += gv * wf4.x; acc[5] += gv * wf4.y; acc[6] += gv * wf4.z; acc[7] += gv * wf4.w;
  }
  #pragma unroll
  for (int o = 0; o < 8; ++o)
    #pragma unroll
    for (int d2 = 1; d2 < 64; d2 <<= 1) acc[o] += __shfl_xor(acc[o], d2);
  int b = row / SS, s = row - b * SS;
  if (lane < 4) {
    ig[((size_t)b * NHH + lane) * SS + s] = acc[lane] + bi[lane];
  } else if (lane < 8) {
    int o = lane - 4;
    fg[((size_t)b * NHH + o) * SS + s] = acc[4 + o] + bfp[o];
  }
}

// ---------------------------------------------------------------------------
// per-(b,h) scan
// ---------------------------------------------------------------------------
__device__ __forceinline__ float logsig(float x) {
  return fminf(x, 0.f) - log1pf(__expf(-fabsf(x)));
}

__global__ __launch_bounds__(64) void scan_kernel(
    const float* __restrict__ fg, const float* __restrict__ ig,
    float* __restrict__ cumf, float* __restrict__ aa, float* __restrict__ MMb)
{
  int bh = blockIdx.x;
  int lane = threadIdx.x;
  const float* f = fg + (size_t)bh * SS;
  const float* g = ig + (size_t)bh * SS;
  int s0 = lane * 14, s1 = s0 + 14; if (s1 > SS) s1 = SS;
  float loc = 0.f;
  for (int s = s0; s < s1; ++s) loc += logsig(f[s]);
  float v = loc;
  #pragma unroll
  for (int d = 1; d < 64; d <<= 1) { float o = __shfl_up(v, d); if (lane >= d) v += o; }
  float run = v - loc;
  float lmax = -1e30f;
  for (int s = s0; s < s1; ++s) {
    run += logsig(f[s]);
    cumf[(size_t)bh * SS + s] = run;
    float a = g[s] - run;
    aa[(size_t)bh * SS + s] = a;
    lmax = fmaxf(lmax, a);
  }
  float mv = lmax;
  #pragma unroll
  for (int d = 1; d < 64; d <<= 1) { float o = __shfl_up(mv, d); if (lane >= d) mv = fmaxf(mv, o); }
  float em = __shfl_up(mv, 1);
  if (lane == 0) em = -1e30f;
  float runm = em;
  for (int s = s0; s < s1; ++s) {
    runm = fmaxf(runm, aa[(size_t)bh * SS + s]);
    MMb[(size_t)bh * SS + s] = runm;
  }
}

// ---------------------------------------------------------------------------
// masked decay attention — split-precision bf16 MFMA (hi/lo, 3-term products).
// Block = (b,h, 64 t's), 4 waves; wave w owns t-rows w*16..w*16+15.
// QK^T: A=Q[t][d], B=K[s][d] (intrinsic takes B as [n][k]); PV: A=W[t][s],
// B=Vt[d][s]. All fragment reads contiguous ds_read_b128; stride 72 bf16.
// ---------------------------------------------------------------------------
__global__ __launch_bounds__(256) void attn_kernel(
    const float* __restrict__ qk, const float* __restrict__ vb,
    const float* __restrict__ cumf, const float* __restrict__ aab,
    const float* __restrict__ MMb, float* __restrict__ hb)
{
  __shared__ u16 Qh[64][72], Ql[64][72];
  __shared__ u16 Kh[64][72], Kl[64][72];
  __shared__ u16 Vh[64][72], Vl[64][72];   // transposed: [d][s]
  __shared__ u16 Wh[64][72], Wl[64][72];   // [t][s]
  __shared__ float a_lds[64];
  int tid = threadIdx.x;
  int wv = tid >> 6, lane = tid & 63;
  int lr = lane & 15, lg = lane >> 4;
  int tb = 13 - blockIdx.x;               // heavy blocks first
  int h = blockIdx.y, b = blockIdx.z;
  int t0 = tb * 64;
  const float* aabh  = aab  + ((size_t)b * NHH + h) * SS;
  const float* Mbh   = MMb  + ((size_t)b * NHH + h) * SS;
  const float* cumbh = cumf + ((size_t)b * NHH + h) * SS;

  // stage Q (prescaled 1/8) as hi/lo bf16
  {
    int row = tid >> 2;
    int t = t0 + row; if (t > SS - 1) t = SS - 1;
    const float* qp = &qk[((size_t)b * SS + t) * 512 + h * 64];
    int d0 = (tid & 3) * 16;
    #pragma unroll
    for (int it = 0; it < 4; ++it) {
      int d = d0 + it * 4;
      float4 qv = *(const float4*)&qp[d];
      float xs[4] = {qv.x * 0.125f, qv.y * 0.125f, qv.z * 0.125f, qv.w * 0.125f};
      u16 hi[4], lo[4];
      #pragma unroll
      for (int j = 0; j < 4; ++j) {
        hi[j] = f2b(xs[j]);
        lo[j] = f2b(xs[j] - b2f(hi[j]));
      }
      *(unsigned*)&Qh[row][d]     = (unsigned)hi[0] | ((unsigned)hi[1] << 16);
      *(unsigned*)&Qh[row][d + 2] = (unsigned)hi[2] | ((unsigned)hi[3] << 16);
      *(unsigned*)&Ql[row][d]     = (unsigned)lo[0] | ((unsigned)lo[1] << 16);
      *(unsigned*)&Ql[row][d + 2] = (unsigned)lo[2] | ((unsigned)lo[3] << 16);
    }
  }
  float Mt[4], nfl[4];
  #pragma unroll
  for (int r = 0; r < 4; ++r) {
    int t = t0 + wv * 16 + lg * 4 + r; int tc = t < SS ? t : SS - 1;
    Mt[r] = Mbh[tc];
    nfl[r] = __expf(-(cumbh[tc] + Mt[r]));
  }
  __syncthreads();
  bf16x8 qh0 = *(const bf16x8*)&Qh[wv * 16 + lr][lg * 8];
  bf16x8 qh1 = *(const bf16x8*)&Qh[wv * 16 + lr][32 + lg * 8];
  bf16x8 ql0 = *(const bf16x8*)&Ql[wv * 16 + lr][lg * 8];
  bf16x8 ql1 = *(const bf16x8*)&Ql[wv * 16 + lr][32 + lg * 8];

  f32x4 hacc[4] = {};
  float wsum[4] = {0.f, 0.f, 0.f, 0.f};
  int tlast = t0 + 63; if (tlast > SS - 1) tlast = SS - 1;
  int ntiles = tlast / 64 + 1;

  for (int st = 0; st < ntiles; ++st) {
    int s0 = st * 64;
    __syncthreads();
    // stage K row-major + V transposed, hi/lo
    {
      int row = tid >> 2;
      int sg = s0 + row;
      bool ok = sg < SS;
      int sc = ok ? sg : SS - 1;
      const float* kp = &qk[((size_t)b * SS + sc) * 512 + 256 + h * 64];
      const float* vp = &vb[((size_t)b * SS + sc) * II + h * 64];
      int d0 = (tid & 3) * 16;
      #pragma unroll
      for (int it = 0; it < 4; ++it) {
        int d = d0 + it * 4;
        float4 kv4 = *(const float4*)&kp[d];
        float4 vv4 = *(const float4*)&vp[d];
        float ks[4] = {kv4.x, kv4.y, kv4.z, kv4.w};
        float vs[4] = {vv4.x, vv4.y, vv4.z, vv4.w};
        if (!ok) { ks[0]=ks[1]=ks[2]=ks[3]=0.f; vs[0]=vs[1]=vs[2]=vs[3]=0.f; }
        u16 khh[4], kll[4];
        #pragma unroll
        for (int j = 0; j < 4; ++j) {
          khh[j] = f2b(ks[j]);
          kll[j] = f2b(ks[j] - b2f(khh[j]));
        }
        *(unsigned*)&Kh[row][d]     = (unsigned)khh[0] | ((unsigned)khh[1] << 16);
        *(unsigned*)&Kh[row][d + 2] = (unsigned)khh[2] | ((unsigned)khh[3] << 16);
        *(unsigned*)&Kl[row][d]     = (unsigned)kll[0] | ((unsigned)kll[1] << 16);
        *(unsigned*)&Kl[row][d + 2] = (unsigned)kll[2] | ((unsigned)kll[3] << 16);
        #pragma unroll
        for (int j = 0; j < 4; ++j) {
          u16 vh_ = f2b(vs[j]);
          u16 vl_ = f2b(vs[j] - b2f(vh_));
          Vh[d + j][row] = vh_;
          Vl[d + j][row] = vl_;
        }
      }
      if (tid < 64) {
        int sgg = s0 + tid;
        a_lds[tid] = (sgg < SS) ? aabh[sgg] : -1e30f;
      }
    }
    __syncthreads();
    float am = a_lds[lane];
    #pragma unroll
    for (int dd = 1; dd < 64; dd <<= 1) am = fmaxf(am, __shfl_xor(am, dd));
    // QK^T (split precision: hh + hl + lh)
    f32x4 p[4];
    #pragma unroll
    for (int sf = 0; sf < 4; ++sf) {
      bf16x8 kh0 = *(const bf16x8*)&Kh[sf * 16 + lr][lg * 8];
      bf16x8 kh1 = *(const bf16x8*)&Kh[sf * 16 + lr][32 + lg * 8];
      bf16x8 kl0 = *(const bf16x8*)&Kl[sf * 16 + lr][lg * 8];
      bf16x8 kl1 = *(const bf16x8*)&Kl[sf * 16 + lr][32 + lg * 8];
      f32x4 acc = {};
      acc = __builtin_amdgcn_mfma_f32_16x16x32_bf16(qh0, kl0, acc, 0, 0, 0);
      acc = __builtin_amdgcn_mfma_f32_16x16x32_bf16(qh1, kl1, acc, 0, 0, 0);
      acc = __builtin_amdgcn_mfma_f32_16x16x32_bf16(ql0, kh0, acc, 0, 0, 0);
      acc = __builtin_amdgcn_mfma_f32_16x16x32_bf16(ql1, kh1, acc, 0, 0, 0);
      acc = __builtin_amdgcn_mfma_f32_16x16x32_bf16(qh0, kh0, acc, 0, 0, 0);
      acc = __builtin_amdgcn_mfma_f32_16x16x32_bf16(qh1, kh1, acc, 0, 0, 0);
      p[sf] = acc;
    }
    // decay + mask + W hi/lo to LDS
    float ee[4], ft[4];
    #pragma unroll
    for (int sf = 0; sf < 4; ++sf) ee[sf] = __expf(a_lds[sf * 16 + lr] - am);
    #pragma unroll
    for (int r = 0; r < 4; ++r) ft[r] = __expf(fminf(am - Mt[r], 80.f));
    #pragma unroll
    for (int sf = 0; sf < 4; ++sf) {
      int s = s0 + sf * 16 + lr;
      #pragma unroll
      for (int r = 0; r < 4; ++r) {
        int t = t0 + wv * 16 + lg * 4 + r;
        float wval = (s <= t) ? p[sf][r] * ee[sf] * ft[r] : 0.f;
        wsum[r] += wval;
        u16 hi_ = f2b(wval);
        u16 lo_ = f2b(wval - b2f(hi_));
        Wh[wv * 16 + lg * 4 + r][sf * 16 + lr] = hi_;
        Wl[wv * 16 + lg * 4 + r][sf * 16 + lr] = lo_;
      }
    }
    __syncthreads();
    // PV: h[t][d] += W · V
    bf16x8 wh0 = *(const bf16x8*)&Wh[wv * 16 + lr][lg * 8];
    bf16x8 wh1 = *(const bf16x8*)&Wh[wv * 16 + lr][32 + lg * 8];
    bf16x8 wl0 = *(const bf16x8*)&Wl[wv * 16 + lr][lg * 8];
    bf16x8 wl1 = *(const bf16x8*)&Wl[wv * 16 + lr][32 + lg * 8];
    #pragma unroll
    for (int df = 0; df < 4; ++df) {
      bf16x8 vh0 = *(const bf16x8*)&Vh[df * 16 + lr][lg * 8];
      bf16x8 vh1 = *(const bf16x8*)&Vh[df * 16 + lr][32 + lg * 8];
      bf16x8 vl0 = *(const bf16x8*)&Vl[df * 16 + lr][lg * 8];
      bf16x8 vl1 = *(const bf16x8*)&Vl[df * 16 + lr][32 + lg * 8];
      f32x4 a2 = hacc[df];
      a2 = __builtin_amdgcn_mfma_f32_16x16x32_bf16(wh0, vl0, a2, 0, 0, 0);
      a2 = __builtin_amdgcn_mfma_f32_16x16x32_bf16(wh1, vl1, a2, 0, 0, 0);
      a2 = __builtin_amdgcn_mfma_f32_16x16x32_bf16(wl0, vh0, a2, 0, 0, 0);
      a2 = __builtin_amdgcn_mfma_f32_16x16x32_bf16(wl1, vh1, a2, 0, 0, 0);
      a2 = __builtin_amdgcn_mfma_f32_16x16x32_bf16(wh0, vh0, a2, 0, 0, 0);
      a2 = __builtin_amdgcn_mfma_f32_16x16x32_bf16(wh1, vh1, a2, 0, 0, 0);
      hacc[df] = a2;
    }
  }
  // reduce wsum over the 16 s-lanes
  #pragma unroll
  for (int r = 0; r < 4; ++r) {
    float sgn = wsum[r];
    sgn += __shfl_xor(sgn, 1); sgn += __shfl_xor(sgn, 2);
    sgn += __shfl_xor(sgn, 4); sgn += __shfl_xor(sgn, 8);
    wsum[r] = sgn;
  }
  #pragma unroll
  for (int r = 0; r < 4; ++r) {
    int t = t0 + wv * 16 + lg * 4 + r;
    if (t < SS) {
      float rn = 1.f / fmaxf(fabsf(wsum[r]), nfl[r]);
      #pragma unroll
      for (int df = 0; df < 4; ++df)
        hb[((size_t)b * SS + t) * II + h * 64 + df * 16 + lr] = hacc[df][r] * rn;
    }
  }
}

// ---------------------------------------------------------------------------
// per-head LN + skip*xc + *silu(z)  -> bf16
// ---------------------------------------------------------------------------
__global__ __launch_bounds__(256) void mhln_kernel(
    const float* __restrict__ up, const float* __restrict__ xc,
    const float* __restrict__ mhg, const float* __restrict__ skip,
    const float* __restrict__ hb, u16* __restrict__ hb_bf)
{
  int row = blockIdx.x;
  int h = threadIdx.x >> 6, lane = threadIdx.x & 63;
  int i = h * DHH + lane;
  float hv = hb[(size_t)row * II + i];
  float s = hv, sq = hv * hv;
  #pragma unroll
  for (int d = 1; d < 64; d <<= 1) { s += __shfl_xor(s, d); sq += __shfl_xor(sq, d); }
  float mu = s * (1.f / 64.f);
  float var = sq * (1.f / 64.f) - mu * mu;
  float hn = (hv - mu) * rsqrtf(var + 1e-5f) * mhg[i];
  float z = up[(size_t)row * 512 + 256 + i];
  float sil = z / (1.f + __expf(-z));
  hb_bf[(size_t)row * II + i] = f2b((hn + skip[i] * xc[(size_t)row * II + i]) * sil);
}

// ---------------------------------------------------------------------------
// final: out[b,p,c] = LN(x)@Wp2^T + bp2 (fp32)
// ---------------------------------------------------------------------------
__global__ __launch_bounds__(256) void final_kernel(
    const float* __restrict__ y, const float* __restrict__ Wp2,
    const float* __restrict__ bp2, float* __restrict__ out)
{
  __shared__ float yl[32 * 132];
  __shared__ float ol[96 * 32];
  int tid = threadIdx.x;
  int blk = blockIdx.x;
  int b = blk / 27, ct = blk % 27;
  int c0 = ct * 32;
  int nc = CC - c0; if (nc > 32) nc = 32;
  for (int j = 0; j < 16; ++j) {
    int idx = tid + j * 256;
    int cl = idx >> 7, d2 = idx & 127;
    yl[cl * 132 + d2] = (cl < nc) ? y[((size_t)b * CC + c0 + cl) * DD + d2] : 0.f;
  }
  __syncthreads();
  for (int j = 0; j < 12; ++j) {
    int o = tid + j * 256;
    int p = o >> 5, cl = o & 31;
    const float* wr = Wp2 + p * 128;
    float acc = bp2[p];
    #pragma unroll 8
    for (int d0 = 0; d0 < 128; d0 += 4) {
      float4 yv = *(const float4*)&yl[cl * 132 + d0];
      float4 wv = *(const float4*)&wr[d0];
      acc += yv.x * wv.x + yv.y * wv.y + yv.z * wv.z + yv.w * wv.w;
    }
    ol[p * 32 + cl] = acc;
  }
  __syncthreads();
  for (int j = 0; j < 12; ++j) {
    int o = tid + j * 256;
    int p = o >> 5, cl = o & 31;
    if (cl < nc) out[(size_t)b * PP * CC + (size_t)p * CC + c0 + cl] = ol[p * 32 + cl];
  }
}

// ---------------------------------------------------------------------------
extern "C" void kernel_launch(void* const* d_in, const int* in_sizes, int n_in,
                              void* d_out, int out_size, void* d_ws, size_t ws_size,
                              hipStream_t stream) {
  const float* xe   = (const float*)d_in[0];
  const float* Ws   = (const float*)d_in[4];
  const float* bs   = (const float*)d_in[5];
  const float* Wt_  = (const float*)d_in[6];
  const float* bt   = (const float*)d_in[7];
  const float* Wp1  = (const float*)d_in[8];
  const float* bp1  = (const float*)d_in[9];
  const float* Wp2  = (const float*)d_in[10];
  const float* bp2  = (const float*)d_in[11];
  const float* lng  = (const float*)d_in[12];
  const float* Wup  = (const float*)d_in[13];
  const float* bup  = (const float*)d_in[14];
  const float* Wcv  = (const float*)d_in[15];
  const float* bcv  = (const float*)d_in[16];
  const float* Wq   = (const float*)d_in[17];
  const float* Wk   = (const float*)d_in[18];
  const float* Wv   = (const float*)d_in[19];
  const float* Wi   = (const float*)d_in[20];
  const float* bi   = (const float*)d_in[21];
  const float* Wf   = (const float*)d_in[22];
  const float* bf_  = (const float*)d_in[23];
  const float* mhg  = (const float*)d_in[24];
  const float* skp  = (const float*)d_in[25];
  const float* Wdn  = (const float*)d_in[26];
  const float* bdn  = (const float*)d_in[27];
  const float* pg   = (const float*)d_in[28];
  float* out = (float*)d_out;

  float* w   = (float*)d_ws;
  float* x   = w;                       // [6896,128]
  float* y   = x   + 882688;
  float* up  = y   + 882688;            // [6896,512]  (aliased by A_head bf16)
  float* xc  = up  + 3530752;           // [6896,256]
  float* qk  = xc  + 1765376;           // [6896,512]
  float* v   = qk  + 3530752;           // [6896,256]
  float* hb  = v   + 1765376;           // [6896,256]
  float* ig  = hb  + 1765376;
  float* fg  = ig  + 27584;
  float* cum = fg  + 27584;
  float* aab = cum + 27584;
  float* MMb = aab + 27584;
  u16* ub    = (u16*)(MMb + 27584);
  u16* y_bf  = ub;            ub += 6896 * 128;
  u16* xc_bf = ub;            ub += 6896 * 256;
  u16* xin_bf = ub;           ub += 6896 * 256;
  u16* hb_bf = ub;            ub += 6896 * 256;
  u16* BTh   = ub;            ub += 131072;
  u16* WupT  = ub;            ub += 131072;   // 2 blocks x [512][128]
  u16* WqkT  = ub;            ub += 262144;
  u16* WvT   = ub;            ub += 131072;
  u16* WdnT  = ub;            ub += 65536;
  float* hbias = (float*)ub;
  u16* Ah = (u16*)up;                   // A_head aliases up

  // weight prep
  tc_kernel<<<dim3(64, 10), 256, 0, stream>>>(Wup, Wq, Wk, Wv, Wdn, WupT, WqkT, WvT, WdnT);
  gcomb_kernel<<<dim3(128, 4), 256, 0, stream>>>(Ws, Wt_, Wp1, BTh);
  hbias_kernel<<<1, 128, 0, stream>>>(bs, bt, Wp1, bp1, hbias);

  // head
  ta_kernel<<<864, 256, 0, stream>>>(xe, Ah);
  gemm_bf16<false, true><<<dim3(2, 108), 256, 0, stream>>>(
      Ah, 1024, BTh, 1024, x, 128, hbias, BC, 128, 1024);

  for (int blk = 0; blk < 2; ++blk) {
    ln_kernel<<<1724, 256, 0, stream>>>(x, lng + blk * 128, y, y_bf, BC);
    gemm_bf16<false, true><<<dim3(8, 108), 256, 0, stream>>>(
        y_bf, 128, WupT + blk * 65536, 128, up, 512, bup + blk * 512, BC, 512, 128);
    conv_silu_kernel<<<6896, 256, 0, stream>>>(up, Wcv + blk * 1024, bcv + blk * 256,
                                               xc, xc_bf, xin_bf);
    gemm_bf16<false, false><<<dim3(8, 108), 256, 0, stream>>>(
        xc_bf, 256, WqkT + blk * 131072, 256, qk, 512, nullptr, BC, 512, 256);
    gemm_bf16<false, false><<<dim3(4, 108), 256, 0, stream>>>(
        xin_bf, 256, WvT + blk * 65536, 256, v, 256, nullptr, BC, 256, 256);
    gates_kernel<<<1724, 256, 0, stream>>>(qk, v, Wi + blk * 3072, bi + blk * 4,
                                           Wf + blk * 3072, bf_ + blk * 4, ig, fg);
    scan_kernel<<<32, 64, 0, stream>>>(fg, ig, cum, aab, MMb);
    attn_kernel<<<dim3(14, 4, 8), 256, 0, stream>>>(qk, v, cum, aab, MMb, hb);
    mhln_kernel<<<6896, 256, 0, stream>>>(up, xc, mhg + blk * 256, skp + blk * 256, hb, hb_bf);
    gemm_bf16<true, true><<<dim3(2, 108), 256, 0, stream>>>(
        hb_bf, 256, WdnT + blk * 32768, 256, x, 128, bdn + blk * 128, BC, 128, 256);
  }

  ln_kernel<<<1724, 256, 0, stream>>>(x, pg, y, y_bf, BC);
  final_kernel<<<216, 256, 0, stream>>>(y, Wp2, bp2, out);
}

// Round 7
// 338.020 us; speedup vs baseline: 9.6511x; 1.0009x over previous
//
#include <hip/hip_runtime.h>
#include <math.h>

#define BB 8
#define LL 512
#define CC 862
#define PP 96
#define DD 128
#define II 256
#define NHH 4
#define DHH 64
#define SS 862
#define BC (BB*CC)

typedef unsigned short u16;
using bf16x8 = __attribute__((ext_vector_type(8))) short;
using f32x4  = __attribute__((ext_vector_type(4))) float;

__device__ __forceinline__ u16 f2b(float x) {
  union { float f; unsigned u; } v; v.f = x;
  unsigned r = v.u + 0x7FFF + ((v.u >> 16) & 1);
  return (u16)(r >> 16);
}
__device__ __forceinline__ float b2f(u16 h) {
  union { unsigned u; float f; } v; v.u = ((unsigned)h) << 16;
  return v.f;
}

// chunk-XOR swizzle: u16 offset of 16B-chunk c within row r of a [64][64] tile
#define XCH(r, c) ((((c) ^ ((r) & 7)) << 3))

// ---------------------------------------------------------------------------
// fused transpose-convert of weights to bf16 [N][K] (Wq scaled by 1/8 exact)
// ---------------------------------------------------------------------------
__global__ __launch_bounds__(256) void tc_kernel(
    const float* __restrict__ Wup, const float* __restrict__ Wq,
    const float* __restrict__ Wk, const float* __restrict__ Wv,
    const float* __restrict__ Wdn,
    u16* __restrict__ WupT, u16* __restrict__ WqkT,
    u16* __restrict__ WvT, u16* __restrict__ WdnT)
{
  const float* src; u16* dst; int R, Cn; float scl = 1.f;
  switch (blockIdx.y) {
    case 0: src = Wup;          dst = WupT;            R = 128; Cn = 512; break;
    case 1: src = Wup + 65536;  dst = WupT + 65536;    R = 128; Cn = 512; break;
    case 2: src = Wq;           dst = WqkT;            R = 256; Cn = 256; scl = 0.125f; break;
    case 3: src = Wk;           dst = WqkT + 65536;    R = 256; Cn = 256; break;
    case 4: src = Wq + 65536;   dst = WqkT + 131072;   R = 256; Cn = 256; scl = 0.125f; break;
    case 5: src = Wk + 65536;   dst = WqkT + 196608;   R = 256; Cn = 256; break;
    case 6: src = Wv;           dst = WvT;             R = 256; Cn = 256; break;
    case 7: src = Wv + 65536;   dst = WvT + 65536;     R = 256; Cn = 256; break;
    case 8: src = Wdn;          dst = WdnT;            R = 256; Cn = 128; break;
    default: src = Wdn + 32768; dst = WdnT + 32768;    R = 256; Cn = 128; break;
  }
  int tpr = Cn >> 5;
  int tx = blockIdx.x % tpr, ty_ = blockIdx.x / tpr;
  if (ty_ >= (R >> 5)) return;
  __shared__ float t[32][33];
  int tid = threadIdx.x;
  int r0 = ty_ * 32, c0 = tx * 32;
  int cr = tid >> 5, cc = tid & 31;
  #pragma unroll
  for (int rr = 0; rr < 4; ++rr)
    t[cr + rr * 8][cc] = src[(size_t)(r0 + cr + rr * 8) * Cn + c0 + cc];
  __syncthreads();
  #pragma unroll
  for (int rr = 0; rr < 4; ++rr)
    dst[(size_t)(c0 + cr + rr * 8) * R + r0 + cc] = f2b(t[cc][cr + rr * 8] * scl);
}

// ---------------------------------------------------------------------------
// combined head weight + bias
// ---------------------------------------------------------------------------
__global__ __launch_bounds__(256) void gcomb_kernel(
    const float* __restrict__ Ws, const float* __restrict__ Wt,
    const float* __restrict__ Wp1, u16* __restrict__ BTh)
{
  int d = blockIdx.x;
  int lp = blockIdx.y * 256 + threadIdx.x;
  const float* wp = Wp1 + d * 96;
  float acc = 0.f;
  if (lp < 512) {
    for (int p = 0; p < 96; ++p) acc += Ws[p * 512 + lp] * wp[p];
  } else {
    int l = lp - 512;
    for (int p = 0; p < 96; ++p) acc += (Wt[p * 512 + l] - Ws[p * 512 + l]) * wp[p];
  }
  BTh[(size_t)d * 1024 + lp] = f2b(acc);
}

__global__ __launch_bounds__(128) void hbias_kernel(
    const float* __restrict__ bs, const float* __restrict__ bt,
    const float* __restrict__ Wp1, const float* __restrict__ bp1,
    float* __restrict__ hbias)
{
  int d = threadIdx.x;
  float acc = bp1[d];
  for (int p = 0; p < 96; ++p) acc += (bs[p] + bt[p]) * Wp1[d * 96 + p];
  hbias[d] = acc;
}

// ---------------------------------------------------------------------------
// gate-weight precombine: Gc = Wq@Wi_q + Wk@Wi_k (and Wf cols), Gv = Wv@Wi_v
// ---------------------------------------------------------------------------
__global__ __launch_bounds__(256) void gprep_kernel(
    const float* __restrict__ Wq, const float* __restrict__ Wk,
    const float* __restrict__ Wv, const float* __restrict__ Wi,
    const float* __restrict__ Wf, float* __restrict__ Gc, float* __restrict__ Gv)
{
  int i = blockIdx.x, blk = blockIdx.y;
  int j = threadIdx.x;
  float wq = Wq[(size_t)blk * 65536 + i * 256 + j];
  float wk = Wk[(size_t)blk * 65536 + i * 256 + j];
  float wv = Wv[(size_t)blk * 65536 + i * 256 + j];
  const float* wi = Wi + blk * 3072;
  const float* wf = Wf + blk * 3072;
  float pc[8], pv[8];
  #pragma unroll
  for (int o = 0; o < 4; ++o) {
    pc[o]     = wq * wi[j * 4 + o] + wk * wi[(256 + j) * 4 + o];
    pc[4 + o] = wq * wf[j * 4 + o] + wk * wf[(256 + j) * 4 + o];
    pv[o]     = wv * wi[(512 + j) * 4 + o];
    pv[4 + o] = wv * wf[(512 + j) * 4 + o];
  }
  #pragma unroll
  for (int o = 0; o < 8; ++o)
    #pragma unroll
    for (int d = 1; d < 64; d <<= 1) {
      pc[o] += __shfl_xor(pc[o], d);
      pv[o] += __shfl_xor(pv[o], d);
    }
  __shared__ float red[4][16];
  int wv_ = j >> 6, lane = j & 63;
  if (lane == 0) {
    #pragma unroll
    for (int o = 0; o < 8; ++o) { red[wv_][o] = pc[o]; red[wv_][8 + o] = pv[o]; }
  }
  __syncthreads();
  if (j < 16) {
    float s4 = red[0][j] + red[1][j] + red[2][j] + red[3][j];
    if (j < 8) Gc[((size_t)blk * 256 + i) * 8 + j] = s4;
    else       Gv[((size_t)blk * 256 + i) * 8 + j - 8] = s4;
  }
}

// ---------------------------------------------------------------------------
// transpose + moving-average -> bf16 A_head [6896][1024]
// ---------------------------------------------------------------------------
__global__ __launch_bounds__(256) void ta_kernel(
    const float* __restrict__ xe, u16* __restrict__ Ah)
{
  __shared__ float xel[8][548];
  __shared__ float mml[8][516];
  int tid = threadIdx.x;
  int b = blockIdx.x / 108, ct = blockIdx.x % 108;
  int c0 = ct * 8;
  for (int j = 0; j < 17; ++j) {
    int idx = tid + j * 256;
    if (idx < 4288) {
      int li = idx >> 3, cl = idx & 7;
      int l = li - 12; l = l < 0 ? 0 : (l > 511 ? 511 : l);
      int c = c0 + cl; if (c > 861) c = 861;
      xel[cl][li] = xe[((size_t)b * LL + l) * CC + c];
    }
  }
  __syncthreads();
  {
    int cl = tid & 7;
    int l0 = (tid >> 3) * 16;
    float win = 0.f;
    #pragma unroll 5
    for (int o = 0; o < 25; ++o) win += xel[cl][l0 + o];
    mml[cl][l0] = win * (1.f / 25.f);
    for (int i = 1; i < 16; ++i) {
      win += xel[cl][l0 + 24 + i] - xel[cl][l0 + i - 1];
      mml[cl][l0 + i] = win * (1.f / 25.f);
    }
  }
  __syncthreads();
  for (int j = 0; j < 32; ++j) {
    int idx = tid + j * 256;
    int cl = idx >> 10, col = idx & 1023;
    int c = c0 + cl;
    if (c < CC) {
      float vsrc = (col < 512) ? xel[cl][12 + col] : mml[cl][col - 512];
      Ah[((size_t)b * CC + c) * 1024 + col] = f2b(vsrc);
    }
  }
}

// ---------------------------------------------------------------------------
// bf16 MFMA GEMM, BK=64.  MODE 0: C=AB+bias; 1: C+=AB+bias; 2: split->Ch/Cl
// ---------------------------------------------------------------------------
template<int MODE>
__global__ __launch_bounds__(256) void gemm_bf16(
    const u16* __restrict__ A, int lda,
    const u16* __restrict__ BT, int ldbt,
    float* __restrict__ C, u16* __restrict__ Ch, u16* __restrict__ Cl,
    int ldc, const float* __restrict__ bias,
    int M, int N, int K)
{
  __shared__ u16 As0[64][40], As1[64][40];
  __shared__ u16 Bs0[64][40], Bs1[64][40];
  int tid = threadIdx.x;
  int m0 = blockIdx.y * 64, n0 = blockIdx.x * 64;
  int wv = tid >> 6, lane = tid & 63;
  int wr = wv >> 1, wc = wv & 1;
  int lrow = lane & 15, lk = lane >> 4;
  f32x4 acc[2][2] = {};
  int arow = tid >> 2, aseg = tid & 3;
  for (int k0 = 0; k0 < K; k0 += 64) {
    int gm = m0 + arow; if (gm > M - 1) gm = M - 1;
    const u16* ap = &A[(size_t)gm * lda + k0 + aseg * 8];
    *(uint4*)&As0[arow][aseg * 8] = *(const uint4*)ap;
    *(uint4*)&As1[arow][aseg * 8] = *(const uint4*)(ap + 32);
    const u16* bp = &BT[(size_t)(n0 + arow) * ldbt + k0 + aseg * 8];
    *(uint4*)&Bs0[arow][aseg * 8] = *(const uint4*)bp;
    *(uint4*)&Bs1[arow][aseg * 8] = *(const uint4*)(bp + 32);
    __syncthreads();
    bf16x8 af[2], bfr[2];
    #pragma unroll
    for (int fm = 0; fm < 2; ++fm) af[fm] = *(const bf16x8*)&As0[wr * 32 + fm * 16 + lrow][lk * 8];
    #pragma unroll
    for (int fn = 0; fn < 2; ++fn) bfr[fn] = *(const bf16x8*)&Bs0[wc * 32 + fn * 16 + lrow][lk * 8];
    #pragma unroll
    for (int fm = 0; fm < 2; ++fm)
      #pragma unroll
      for (int fn = 0; fn < 2; ++fn)
        acc[fm][fn] = __builtin_amdgcn_mfma_f32_16x16x32_bf16(af[fm], bfr[fn], acc[fm][fn], 0, 0, 0);
    #pragma unroll
    for (int fm = 0; fm < 2; ++fm) af[fm] = *(const bf16x8*)&As1[wr * 32 + fm * 16 + lrow][lk * 8];
    #pragma unroll
    for (int fn = 0; fn < 2; ++fn) bfr[fn] = *(const bf16x8*)&Bs1[wc * 32 + fn * 16 + lrow][lk * 8];
    #pragma unroll
    for (int fm = 0; fm < 2; ++fm)
      #pragma unroll
      for (int fn = 0; fn < 2; ++fn)
        acc[fm][fn] = __builtin_amdgcn_mfma_f32_16x16x32_bf16(af[fm], bfr[fn], acc[fm][fn], 0, 0, 0);
    __syncthreads();
  }
  #pragma unroll
  for (int fm = 0; fm < 2; ++fm) {
    #pragma unroll
    for (int fn = 0; fn < 2; ++fn) {
      int col = n0 + wc * 32 + fn * 16 + lrow;
      #pragma unroll
      for (int r = 0; r < 4; ++r) {
        int row = m0 + wr * 32 + fm * 16 + lk * 4 + r;
        if (row < M) {
          float vv = acc[fm][fn][r];
          if (MODE == 0 || MODE == 1) {
            if (bias) vv += bias[col];
            float* cp = &C[(size_t)row * ldc + col];
            if (MODE == 1) vv += *cp;
            *cp = vv;
          } else {
            u16 hi = f2b(vv);
            u16 lo = f2b(vv - b2f(hi));
            Ch[(size_t)row * ldc + col] = hi;
            Cl[(size_t)row * ldc + col] = lo;
          }
        }
      }
    }
  }
}

// ---------------------------------------------------------------------------
// Row LayerNorm (D=128): writes fp32 + bf16
// ---------------------------------------------------------------------------
__global__ __launch_bounds__(256) void ln_kernel(
    const float* __restrict__ x, const float* __restrict__ g,
    float* __restrict__ y, u16* __restrict__ y_bf, int nrows)
{
  int row = blockIdx.x * 4 + (threadIdx.x >> 6);
  int lane = threadIdx.x & 63;
  if (row >= nrows) return;
  const float* xr = x + (size_t)row * DD;
  float a = xr[lane], b2 = xr[lane + 64];
  float s = a + b2, sq = a * a + b2 * b2;
  #pragma unroll
  for (int d = 1; d < 64; d <<= 1) { s += __shfl_xor(s, d); sq += __shfl_xor(sq, d); }
  float mean = s * (1.f / 128.f);
  float var = sq * (1.f / 128.f) - mean * mean;
  float r = rsqrtf(var + 1e-5f);
  float v0 = (a - mean) * r * g[lane];
  float v1 = (b2 - mean) * r * g[64 + lane];
  y[(size_t)row * DD + lane] = v0;
  y[(size_t)row * DD + 64 + lane] = v1;
  y_bf[(size_t)row * DD + lane] = f2b(v0);
  y_bf[(size_t)row * DD + 64 + lane] = f2b(v1);
}

// ---------------------------------------------------------------------------
// causal conv (k=4) + SiLU + fused gate preacts (via Gc/Gv)
// ---------------------------------------------------------------------------
__global__ __launch_bounds__(256) void conv_gates_kernel(
    const float* __restrict__ up, const float* __restrict__ Wc,
    const float* __restrict__ bc, const float* __restrict__ Gc,
    const float* __restrict__ Gv, const float* __restrict__ bi,
    const float* __restrict__ bfp,
    float* __restrict__ xc, u16* __restrict__ xc_bf, u16* __restrict__ xin_bf,
    float* __restrict__ ig, float* __restrict__ fg)
{
  __shared__ float red[4][8];
  int row = blockIdx.x;
  int i = threadIdx.x;
  int b = row / SS, s = row - b * SS;
  float acc = bc[i];
  float xin = 0.f;
  #pragma unroll
  for (int w2 = 0; w2 < 4; ++w2) {
    int sp = s - 3 + w2;
    if (sp >= 0) {
      float uv = up[((size_t)b * SS + sp) * 512 + i];
      acc += uv * Wc[w2 * 256 + i];
      if (w2 == 3) xin = uv;
    }
  }
  float sg = 1.f / (1.f + __expf(-acc));
  float val = acc * sg;
  xc[(size_t)row * II + i] = val;
  xc_bf[(size_t)row * II + i] = f2b(val);
  xin_bf[(size_t)row * II + i] = f2b(xin);
  // fused gates
  float p[8];
  const float* gci = &Gc[i * 8];
  const float* gvi = &Gv[i * 8];
  #pragma unroll
  for (int o = 0; o < 8; ++o) p[o] = val * gci[o] + xin * gvi[o];
  #pragma unroll
  for (int o = 0; o < 8; ++o)
    #pragma unroll
    for (int d = 1; d < 64; d <<= 1) p[o] += __shfl_xor(p[o], d);
  int wv = i >> 6, lane = i & 63;
  if (lane == 0) {
    #pragma unroll
    for (int o = 0; o < 8; ++o) red[wv][o] = p[o];
  }
  __syncthreads();
  if (i < 8) {
    float sum = red[0][i] + red[1][i] + red[2][i] + red[3][i];
    if (i < 4) ig[((size_t)b * NHH + i) * SS + s] = sum + bi[i];
    else       fg[((size_t)b * NHH + i - 4) * SS + s] = sum + bfp[i - 4];
  }
}

// ---------------------------------------------------------------------------
// per-(b,h) scan
// ---------------------------------------------------------------------------
__device__ __forceinline__ float logsig(float x) {
  return fminf(x, 0.f) - log1pf(__expf(-fabsf(x)));
}

__global__ __launch_bounds__(64) void scan_kernel(
    const float* __restrict__ fg, const float* __restrict__ ig,
    float* __restrict__ cumf, float* __restrict__ aa, float* __restrict__ MMb)
{
  int bh = blockIdx.x;
  int lane = threadIdx.x;
  const float* f = fg + (size_t)bh * SS;
  const float* g = ig + (size_t)bh * SS;
  int s0 = lane * 14, s1 = s0 + 14; if (s1 > SS) s1 = SS;
  float loc = 0.f;
  for (int s = s0; s < s1; ++s) loc += logsig(f[s]);
  float v = loc;
  #pragma unroll
  for (int d = 1; d < 64; d <<= 1) { float o = __shfl_up(v, d); if (lane >= d) v += o; }
  float run = v - loc;
  float lmax = -1e30f;
  for (int s = s0; s < s1; ++s) {
    run += logsig(f[s]);
    cumf[(size_t)bh * SS + s] = run;
    float a = g[s] - run;
    aa[(size_t)bh * SS + s] = a;
    lmax = fmaxf(lmax, a);
  }
  float mv = lmax;
  #pragma unroll
  for (int d = 1; d < 64; d <<= 1) { float o = __shfl_up(mv, d); if (lane >= d) mv = fmaxf(mv, o); }
  float em = __shfl_up(mv, 1);
  if (lane == 0) em = -1e30f;
  float runm = em;
  for (int s = s0; s < s1; ++s) {
    runm = fmaxf(runm, aa[(size_t)bh * SS + s]);
    MMb[(size_t)bh * SS + s] = runm;
  }
}

// ---------------------------------------------------------------------------
// masked decay attention — split-precision MFMA, pre-split inputs,
// chunk-XOR swizzled [64][64] LDS tiles (conflict-free b128 frags).
// ---------------------------------------------------------------------------
__global__ __launch_bounds__(256) void attn_kernel(
    const u16* __restrict__ qkh, const u16* __restrict__ qkl,
    const u16* __restrict__ vhg, const u16* __restrict__ vlg,
    const float* __restrict__ cumf, const float* __restrict__ aab,
    const float* __restrict__ MMb, float* __restrict__ hb)
{
  __shared__ u16 Qh[64][64], Ql[64][64];
  __shared__ u16 Kh[64][64], Kl[64][64];
  __shared__ u16 Vh[64][64], Vl[64][64];   // transposed: [d][s]
  __shared__ u16 Wh[64][64], Wl[64][64];   // [t][s]
  __shared__ float a_lds[64];
  int tid = threadIdx.x;
  int wv = tid >> 6, lane = tid & 63;
  int lr = lane & 15, lg = lane >> 4;
  int tb = 13 - blockIdx.x;
  int h = blockIdx.y, b = blockIdx.z;
  int t0 = tb * 64;
  const float* aabh  = aab  + ((size_t)b * NHH + h) * SS;
  const float* Mbh   = MMb  + ((size_t)b * NHH + h) * SS;
  const float* cumbh = cumf + ((size_t)b * NHH + h) * SS;

  // stage Q (already 1/8-scaled via WqT) — pure u16 copy, swizzled
  {
    int row = tid >> 2, seg = tid & 3;
    int t = t0 + row; if (t > SS - 1) t = SS - 1;
    const u16* qp = qkh + ((size_t)b * SS + t) * 512 + h * 64 + seg * 16;
    const u16* ql_ = qkl + ((size_t)b * SS + t) * 512 + h * 64 + seg * 16;
    *(uint4*)&Qh[row][XCH(row, 2 * seg)]     = *(const uint4*)qp;
    *(uint4*)&Qh[row][XCH(row, 2 * seg + 1)] = *(const uint4*)(qp + 8);
    *(uint4*)&Ql[row][XCH(row, 2 * seg)]     = *(const uint4*)ql_;
    *(uint4*)&Ql[row][XCH(row, 2 * seg + 1)] = *(const uint4*)(ql_ + 8);
  }
  float Mt[4], nfl[4];
  #pragma unroll
  for (int r = 0; r < 4; ++r) {
    int t = t0 + wv * 16 + lg * 4 + r; int tc = t < SS ? t : SS - 1;
    Mt[r] = Mbh[tc];
    nfl[r] = __expf(-(cumbh[tc] + Mt[r]));
  }
  __syncthreads();
  int qr = wv * 16 + lr;
  bf16x8 qh0 = *(const bf16x8*)&Qh[qr][XCH(qr, lg)];
  bf16x8 qh1 = *(const bf16x8*)&Qh[qr][XCH(qr, lg + 4)];
  bf16x8 ql0 = *(const bf16x8*)&Ql[qr][XCH(qr, lg)];
  bf16x8 ql1 = *(const bf16x8*)&Ql[qr][XCH(qr, lg + 4)];

  f32x4 hacc[4] = {};
  float wsum[4] = {0.f, 0.f, 0.f, 0.f};
  int tlast = t0 + 63; if (tlast > SS - 1) tlast = SS - 1;
  int ntiles = tlast / 64 + 1;

  for (int st = 0; st < ntiles; ++st) {
    int s0 = st * 64;
    __syncthreads();
    // stage K (row-major, swizzled) + V (transposed, swizzled)
    {
      int row = tid >> 2, seg = tid & 3;
      int sg = s0 + row;
      bool ok = sg < SS;
      int sc = ok ? sg : SS - 1;
      const u16* kp = qkh + ((size_t)b * SS + sc) * 512 + 256 + h * 64 + seg * 16;
      const u16* kl_ = qkl + ((size_t)b * SS + sc) * 512 + 256 + h * 64 + seg * 16;
      uint4 zero = make_uint4(0, 0, 0, 0);
      uint4 a0 = ok ? *(const uint4*)kp : zero;
      uint4 a1 = ok ? *(const uint4*)(kp + 8) : zero;
      uint4 a2 = ok ? *(const uint4*)kl_ : zero;
      uint4 a3 = ok ? *(const uint4*)(kl_ + 8) : zero;
      *(uint4*)&Kh[row][XCH(row, 2 * seg)]     = a0;
      *(uint4*)&Kh[row][XCH(row, 2 * seg + 1)] = a1;
      *(uint4*)&Kl[row][XCH(row, 2 * seg)]     = a2;
      *(uint4*)&Kl[row][XCH(row, 2 * seg + 1)] = a3;
      const u16* vp = vhg + ((size_t)b * SS + sc) * II + h * 64 + seg * 16;
      const u16* vl_ = vlg + ((size_t)b * SS + sc) * II + h * 64 + seg * 16;
      uint4 b0 = ok ? *(const uint4*)vp : zero;
      uint4 b1 = ok ? *(const uint4*)(vp + 8) : zero;
      uint4 b2v = ok ? *(const uint4*)vl_ : zero;
      uint4 b3 = ok ? *(const uint4*)(vl_ + 8) : zero;
      u16 th[16], tl[16];
      *(uint4*)&th[0] = b0; *(uint4*)&th[8] = b1;
      *(uint4*)&tl[0] = b2v; *(uint4*)&tl[8] = b3;
      int rc = row >> 3, rb = row & 7;
      #pragma unroll
      for (int j = 0; j < 16; ++j) {
        int d = seg * 16 + j;
        Vh[d][XCH(d, rc) + rb] = th[j];
        Vl[d][XCH(d, rc) + rb] = tl[j];
      }
      if (tid < 64) {
        int sgg = s0 + tid;
        a_lds[tid] = (sgg < SS) ? aabh[sgg] : -1e30f;
      }
    }
    __syncthreads();
    float am = a_lds[lane];
    #pragma unroll
    for (int dd = 1; dd < 64; dd <<= 1) am = fmaxf(am, __shfl_xor(am, dd));
    // QK^T split: hh + hl + lh
    f32x4 p[4];
    #pragma unroll
    for (int sf = 0; sf < 4; ++sf) {
      int sr = sf * 16 + lr;
      bf16x8 kh0 = *(const bf16x8*)&Kh[sr][XCH(sr, lg)];
      bf16x8 kh1 = *(const bf16x8*)&Kh[sr][XCH(sr, lg + 4)];
      bf16x8 kl0 = *(const bf16x8*)&Kl[sr][XCH(sr, lg)];
      bf16x8 kl1 = *(const bf16x8*)&Kl[sr][XCH(sr, lg + 4)];
      f32x4 acc = {};
      acc = __builtin_amdgcn_mfma_f32_16x16x32_bf16(qh0, kl0, acc, 0, 0, 0);
      acc = __builtin_amdgcn_mfma_f32_16x16x32_bf16(qh1, kl1, acc, 0, 0, 0);
      acc = __builtin_amdgcn_mfma_f32_16x16x32_bf16(ql0, kh0, acc, 0, 0, 0);
      acc = __builtin_amdgcn_mfma_f32_16x16x32_bf16(ql1, kh1, acc, 0, 0, 0);
      acc = __builtin_amdgcn_mfma_f32_16x16x32_bf16(qh0, kh0, acc, 0, 0, 0);
      acc = __builtin_amdgcn_mfma_f32_16x16x32_bf16(qh1, kh1, acc, 0, 0, 0);
      p[sf] = acc;
    }
    // decay + mask + W hi/lo to LDS (swizzled)
    float ee[4], ft[4];
    #pragma unroll
    for (int sf = 0; sf < 4; ++sf) ee[sf] = __expf(a_lds[sf * 16 + lr] - am);
    #pragma unroll
    for (int r = 0; r < 4; ++r) ft[r] = __expf(fminf(am - Mt[r], 80.f));
    #pragma unroll
    for (int sf = 0; sf < 4; ++sf) {
      int s = s0 + sf * 16 + lr;
      int sc_ = sf * 2 + (lr >> 3), sb = lr & 7;
      #pragma unroll
      for (int r = 0; r < 4; ++r) {
        int tl_ = wv * 16 + lg * 4 + r;
        int t = t0 + tl_;
        float wval = (s <= t) ? p[sf][r] * ee[sf] * ft[r] : 0.f;
        wsum[r] += wval;
        u16 hi_ = f2b(wval);
        u16 lo_ = f2b(wval - b2f(hi_));
        Wh[tl_][XCH(tl_, sc_) + sb] = hi_;
        Wl[tl_][XCH(tl_, sc_) + sb] = lo_;
      }
    }
    __syncthreads();
    // PV: h[t][d] += W · V
    int tr = wv * 16 + lr;
    bf16x8 wh0 = *(const bf16x8*)&Wh[tr][XCH(tr, lg)];
    bf16x8 wh1 = *(const bf16x8*)&Wh[tr][XCH(tr, lg + 4)];
    bf16x8 wl0 = *(const bf16x8*)&Wl[tr][XCH(tr, lg)];
    bf16x8 wl1 = *(const bf16x8*)&Wl[tr][XCH(tr, lg + 4)];
    #pragma unroll
    for (int df = 0; df < 4; ++df) {
      int dr = df * 16 + lr;
      bf16x8 vh0 = *(const bf16x8*)&Vh[dr][XCH(dr, lg)];
      bf16x8 vh1 = *(const bf16x8*)&Vh[dr][XCH(dr, lg + 4)];
      bf16x8 vl0 = *(const bf16x8*)&Vl[dr][XCH(dr, lg)];
      bf16x8 vl1 = *(const bf16x8*)&Vl[dr][XCH(dr, lg + 4)];
      f32x4 a2 = hacc[df];
      a2 = __builtin_amdgcn_mfma_f32_16x16x32_bf16(wh0, vl0, a2, 0, 0, 0);
      a2 = __builtin_amdgcn_mfma_f32_16x16x32_bf16(wh1, vl1, a2, 0, 0, 0);
      a2 = __builtin_amdgcn_mfma_f32_16x16x32_bf16(wl0, vh0, a2, 0, 0, 0);
      a2 = __builtin_amdgcn_mfma_f32_16x16x32_bf16(wl1, vh1, a2, 0, 0, 0);
      a2 = __builtin_amdgcn_mfma_f32_16x16x32_bf16(wh0, vh0, a2, 0, 0, 0);
      a2 = __builtin_amdgcn_mfma_f32_16x16x32_bf16(wh1, vh1, a2, 0, 0, 0);
      hacc[df] = a2;
    }
  }
  #pragma unroll
  for (int r = 0; r < 4; ++r) {
    float sgn = wsum[r];
    sgn += __shfl_xor(sgn, 1); sgn += __shfl_xor(sgn, 2);
    sgn += __shfl_xor(sgn, 4); sgn += __shfl_xor(sgn, 8);
    wsum[r] = sgn;
  }
  #pragma unroll
  for (int r = 0; r < 4; ++r) {
    int t = t0 + wv * 16 + lg * 4 + r;
    if (t < SS) {
      float rn = 1.f / fmaxf(fabsf(wsum[r]), nfl[r]);
      #pragma unroll
      for (int df = 0; df < 4; ++df)
        hb[((size_t)b * SS + t) * II + h * 64 + df * 16 + lr] = hacc[df][r] * rn;
    }
  }
}

// ---------------------------------------------------------------------------
// per-head LN + skip*xc + *silu(z)  -> bf16
// ---------------------------------------------------------------------------
__global__ __launch_bounds__(256) void mhln_kernel(
    const float* __restrict__ up, const float* __restrict__ xc,
    const float* __restrict__ mhg, const float* __restrict__ skip,
    const float* __restrict__ hb, u16* __restrict__ hb_bf)
{
  int row = blockIdx.x;
  int h = threadIdx.x >> 6, lane = threadIdx.x & 63;
  int i = h * DHH + lane;
  float hv = hb[(size_t)row * II + i];
  float s = hv, sq = hv * hv;
  #pragma unroll
  for (int d = 1; d < 64; d <<= 1) { s += __shfl_xor(s, d); sq += __shfl_xor(sq, d); }
  float mu = s * (1.f / 64.f);
  float var = sq * (1.f / 64.f) - mu * mu;
  float hn = (hv - mu) * rsqrtf(var + 1e-5f) * mhg[i];
  float z = up[(size_t)row * 512 + 256 + i];
  float sil = z / (1.f + __expf(-z));
  hb_bf[(size_t)row * II + i] = f2b((hn + skip[i] * xc[(size_t)row * II + i]) * sil);
}

// ---------------------------------------------------------------------------
// final: out[b,p,c] = LN(x)@Wp2^T + bp2 (fp32)
// ---------------------------------------------------------------------------
__global__ __launch_bounds__(256) void final_kernel(
    const float* __restrict__ y, const float* __restrict__ Wp2,
    const float* __restrict__ bp2, float* __restrict__ out)
{
  __shared__ float yl[32 * 132];
  __shared__ float ol[96 * 32];
  int tid = threadIdx.x;
  int blk = blockIdx.x;
  int b = blk / 27, ct = blk % 27;
  int c0 = ct * 32;
  int nc = CC - c0; if (nc > 32) nc = 32;
  for (int j = 0; j < 16; ++j) {
    int idx = tid + j * 256;
    int cl = idx >> 7, d2 = idx & 127;
    yl[cl * 132 + d2] = (cl < nc) ? y[((size_t)b * CC + c0 + cl) * DD + d2] : 0.f;
  }
  __syncthreads();
  for (int j = 0; j < 12; ++j) {
    int o = tid + j * 256;
    int p = o >> 5, cl = o & 31;
    const float* wr = Wp2 + p * 128;
    float acc = bp2[p];
    #pragma unroll 8
    for (int d0 = 0; d0 < 128; d0 += 4) {
      float4 yv = *(const float4*)&yl[cl * 132 + d0];
      float4 wv = *(const float4*)&wr[d0];
      acc += yv.x * wv.x + yv.y * wv.y + yv.z * wv.z + yv.w * wv.w;
    }
    ol[p * 32 + cl] = acc;
  }
  __syncthreads();
  for (int j = 0; j < 12; ++j) {
    int o = tid + j * 256;
    int p = o >> 5, cl = o & 31;
    if (cl < nc) out[(size_t)b * PP * CC + (size_t)p * CC + c0 + cl] = ol[p * 32 + cl];
  }
}

// ---------------------------------------------------------------------------
extern "C" void kernel_launch(void* const* d_in, const int* in_sizes, int n_in,
                              void* d_out, int out_size, void* d_ws, size_t ws_size,
                              hipStream_t stream) {
  const float* xe   = (const float*)d_in[0];
  const float* Ws   = (const float*)d_in[4];
  const float* bs   = (const float*)d_in[5];
  const float* Wt_  = (const float*)d_in[6];
  const float* bt   = (const float*)d_in[7];
  const float* Wp1  = (const float*)d_in[8];
  const float* bp1  = (const float*)d_in[9];
  const float* Wp2  = (const float*)d_in[10];
  const float* bp2  = (const float*)d_in[11];
  const float* lng  = (const float*)d_in[12];
  const float* Wup  = (const float*)d_in[13];
  const float* bup  = (const float*)d_in[14];
  const float* Wcv  = (const float*)d_in[15];
  const float* bcv  = (const float*)d_in[16];
  const float* Wq   = (const float*)d_in[17];
  const float* Wk   = (const float*)d_in[18];
  const float* Wv   = (const float*)d_in[19];
  const float* Wi   = (const float*)d_in[20];
  const float* bi   = (const float*)d_in[21];
  const float* Wf   = (const float*)d_in[22];
  const float* bf_  = (const float*)d_in[23];
  const float* mhg  = (const float*)d_in[24];
  const float* skp  = (const float*)d_in[25];
  const float* Wdn  = (const float*)d_in[26];
  const float* bdn  = (const float*)d_in[27];
  const float* pg   = (const float*)d_in[28];
  float* out = (float*)d_out;

  float* w   = (float*)d_ws;
  float* x   = w;                       // [6896,128]
  float* y   = x   + 882688;
  float* up  = y   + 882688;            // [6896,512]  (aliased by A_head bf16)
  float* xc  = up  + 3530752;           // [6896,256]
  float* hb  = xc  + 1765376;           // [6896,256]
  float* ig  = hb  + 1765376;
  float* fg  = ig  + 27584;
  float* cum = fg  + 27584;
  float* aab = cum + 27584;
  float* MMb = aab + 27584;
  float* hbias = MMb + 27584;
  float* Gc  = hbias + 128;             // [2][256][8]
  float* Gv  = Gc + 4096;
  u16* ub    = (u16*)(Gv + 4096);
  u16* y_bf  = ub;            ub += 6896 * 128;
  u16* xc_bf = ub;            ub += 6896 * 256;
  u16* xin_bf = ub;           ub += 6896 * 256;
  u16* hb_bf = ub;            ub += 6896 * 256;
  u16* qkh   = ub;            ub += 6896 * 512;
  u16* qkl   = ub;            ub += 6896 * 512;
  u16* vh    = ub;            ub += 6896 * 256;
  u16* vl    = ub;            ub += 6896 * 256;
  u16* BTh   = ub;            ub += 131072;
  u16* WupT  = ub;            ub += 131072;
  u16* WqkT  = ub;            ub += 262144;
  u16* WvT   = ub;            ub += 131072;
  u16* WdnT  = ub;            ub += 65536;
  u16* Ah = (u16*)up;                   // A_head aliases up

  // weight prep
  tc_kernel<<<dim3(64, 10), 256, 0, stream>>>(Wup, Wq, Wk, Wv, Wdn, WupT, WqkT, WvT, WdnT);
  gcomb_kernel<<<dim3(128, 4), 256, 0, stream>>>(Ws, Wt_, Wp1, BTh);
  hbias_kernel<<<1, 128, 0, stream>>>(bs, bt, Wp1, bp1, hbias);
  gprep_kernel<<<dim3(256, 2), 256, 0, stream>>>(Wq, Wk, Wv, Wi, Wf, Gc, Gv);

  // head
  ta_kernel<<<864, 256, 0, stream>>>(xe, Ah);
  gemm_bf16<0><<<dim3(2, 108), 256, 0, stream>>>(
      Ah, 1024, BTh, 1024, x, nullptr, nullptr, 128, hbias, BC, 128, 1024);

  for (int blk = 0; blk < 2; ++blk) {
    ln_kernel<<<1724, 256, 0, stream>>>(x, lng + blk * 128, y, y_bf, BC);
    gemm_bf16<0><<<dim3(8, 108), 256, 0, stream>>>(
        y_bf, 128, WupT + blk * 65536, 128, up, nullptr, nullptr, 512,
        bup + blk * 512, BC, 512, 128);
    conv_gates_kernel<<<6896, 256, 0, stream>>>(
        up, Wcv + blk * 1024, bcv + blk * 256, Gc + blk * 2048, Gv + blk * 2048,
        bi + blk * 4, bf_ + blk * 4, xc, xc_bf, xin_bf, ig, fg);
    gemm_bf16<2><<<dim3(8, 108), 256, 0, stream>>>(
        xc_bf, 256, WqkT + blk * 131072, 256, nullptr, qkh, qkl, 512,
        nullptr, BC, 512, 256);
    gemm_bf16<2><<<dim3(4, 108), 256, 0, stream>>>(
        xin_bf, 256, WvT + blk * 65536, 256, nullptr, vh, vl, 256,
        nullptr, BC, 256, 256);
    scan_kernel<<<32, 64, 0, stream>>>(fg, ig, cum, aab, MMb);
    attn_kernel<<<dim3(14, 4, 8), 256, 0, stream>>>(qkh, qkl, vh, vl, cum, aab, MMb, hb);
    mhln_kernel<<<6896, 256, 0, stream>>>(up, xc, mhg + blk * 256, skp + blk * 256, hb, hb_bf);
    gemm_bf16<1><<<dim3(2, 108), 256, 0, stream>>>(
        hb_bf, 256, WdnT + blk * 32768, 256, x, nullptr, nullptr, 128,
        bdn + blk * 128, BC, 128, 256);
  }

  ln_kernel<<<1724, 256, 0, stream>>>(x, pg, y, y_bf, BC);
  final_kernel<<<216, 256, 0, stream>>>(y, Wp2, bp2, out);
}